// Round 9
// baseline (221.323 us; speedup 1.0000x reference)
//
#include <hip/hip_runtime.h>
#include <hip/hip_bf16.h>

#define HS 64
#define NH 16
#define NG 16
#define TT 2048
#define CC 1024
#define BBATCH 4
#define TG 128
#define SS 129   // TG+1

typedef __attribute__((ext_vector_type(8))) short bf16x8;
typedef __attribute__((ext_vector_type(4))) float f32x4;

__device__ __forceinline__ float bf2f(ushort u) {
  return __uint_as_float(((unsigned)u) << 16);
}
__device__ __forceinline__ ushort f2bf(float f) {
  unsigned x = __float_as_uint(f);
  x += 0x7fff + ((x >> 16) & 1);
  return (ushort)(x >> 16);
}
__device__ __forceinline__ bf16x8 mk8(ushort4 a0, ushort4 a1) {
  bf16x8 v;
  v[0] = (short)a0.x; v[1] = (short)a0.y; v[2] = (short)a0.z; v[3] = (short)a0.w;
  v[4] = (short)a1.x; v[5] = (short)a1.y; v[6] = (short)a1.z; v[7] = (short)a1.w;
  return v;
}
__device__ __forceinline__ void load_lds16(const ushort* g, ushort* l) {
  __builtin_amdgcn_global_load_lds((const __attribute__((address_space(1))) unsigned int*)g,
                                   (__attribute__((address_space(3))) unsigned int*)l, 16, 0, 0);
}

// ---------------- fp32 -> bf16 convert ----------------
__global__ void cvt_f32_bf16(const float* __restrict__ src, ushort* __restrict__ dst, int n4) {
  int stride = gridDim.x * blockDim.x;
  for (int i = blockIdx.x * blockDim.x + threadIdx.x; i < n4; i += stride) {
    float4 v = ((const float4*)src)[i];
    ushort4 o;
    o.x = f2bf(v.x); o.y = f2bf(v.y); o.z = f2bf(v.z); o.w = f2bf(v.w);
    ((ushort4*)dst)[i] = o;
  }
}

// ---------------- 8-phase-style pipelined GEMM: C[m][n] = sum_k A[m][k]*Bw[n][k] ----------------
// BM=256 BN=128 BK=64, 8 waves (4Mx2N, 64x64 per wave). A double-buffered (stage t+1),
// B triple-buffered (stage t+2). Tile-top s_waitcnt vmcnt(2) (counted, never 0 mid-loop).
// T2 XOR-swizzle: linear global_load_lds dest + inverse-swizzled global source
// (col ^= (row&7)*8 elems) + same XOR on ds_read -> per-chunk identity, conflict-free.
template <bool OUT_BF16>
__global__ __launch_bounds__(512, 2) void gemm8p(const ushort* __restrict__ A,
                                                 const ushort* __restrict__ Bw,
                                                 void* __restrict__ Cout,
                                                 int N, int K, int nx) {
  __shared__ ushort Ab[2 * 256 * 64];   // 64 KB
  __shared__ ushort Bb[3 * 128 * 64];   // 48 KB
  const int tid = threadIdx.x;
  const int w = tid >> 6, lane = tid & 63;
  const int lo = lane & 15, hi4 = lane >> 4;
  const int wm = w >> 1, wn = w & 1;
  // XCD-aware swizzle of the 1D grid (gridDim.x % 8 == 0 for both call sites)
  const int nwg = gridDim.x;
  const int cpx = nwg >> 3;
  const int bid = blockIdx.x;
  const int swz = (bid & 7) * cpx + (bid >> 3);
  const int n0 = (swz % nx) * 128;
  const int m0 = (swz / nx) * 256;
  const int srow = lane >> 3;                         // 0..7
  const int scol = ((lane & 7) * 8) ^ (srow << 3);    // inverse-swizzled global col
  const int nt = K >> 6;

  const ushort* Ag = A + (size_t)(m0 + w * 8 + srow) * K + scol;
  const ushort* Bg = Bw + (size_t)(n0 + w * 8 + srow) * K + scol;

  f32x4 acc[4][4];
#pragma unroll
  for (int i = 0; i < 4; ++i)
#pragma unroll
    for (int j = 0; j < 4; ++j) acc[i][j] = (f32x4)0.0f;

  // frag-read swizzled column offsets (elems)
  const int cx = (lane & 7) << 3;
  const int c0 = (8 * hi4) ^ cx;
  const int c1 = (32 + 8 * hi4) ^ cx;
  const int rowA = (wm * 64 + lo) * 64;
  const int rowB = (wn * 64 + lo) * 64;

#define STG_A2(tt, ab, p0)                                                          \
  {                                                                                 \
    load_lds16(Ag + (size_t)((p0) * 64) * K + (tt) * 64,                            \
               Ab + (ab) * 16384 + (p0) * 4096 + w * 512);                          \
    load_lds16(Ag + (size_t)((p0) * 64 + 64) * K + (tt) * 64,                       \
               Ab + (ab) * 16384 + ((p0) + 1) * 4096 + w * 512);                    \
  }
#define STG_B(tt, bb)                                                               \
  {                                                                                 \
    load_lds16(Bg + (tt) * 64, Bb + (bb) * 8192 + w * 512);                         \
    load_lds16(Bg + (size_t)64 * K + (tt) * 64, Bb + (bb) * 8192 + 4096 + w * 512); \
  }

  // prologue: A(0) x4, B(0) x2, B(1) x2  -> wait all but newest 2 (= B(1))
  STG_A2(0, 0, 0)
  STG_A2(0, 0, 2)
  STG_B(0, 0)
  STG_B(1, 1)
  asm volatile("s_waitcnt vmcnt(2)" ::: "memory");
  __builtin_amdgcn_s_barrier();
  __builtin_amdgcn_sched_barrier(0);

  int acur = 0, bcur = 0, bs1 = 1, bs2 = 2;
  for (int t = 0; t < nt; ++t) {
    if (t > 0) {
      if (t < nt - 1) {
        asm volatile("s_waitcnt vmcnt(2)" ::: "memory");
      } else {
        asm volatile("s_waitcnt vmcnt(0)" ::: "memory");
      }
      __builtin_amdgcn_s_barrier();
      __builtin_amdgcn_sched_barrier(0);
    }
    const ushort* Ac = Ab + acur * 16384;
    const ushort* Bc = Bb + bcur * 8192;
    const int an = acur ^ 1;
    const bool pfA = (t + 1) < nt;
    const bool pfB = (t + 2) < nt;
    bf16x8 bfrag[4][2];
    bf16x8 a0, a1;

    // ---- phase 0: stage A(t+1) p0,p1 | read B all + A[0] | MFMA i=0 ----
    if (pfA) STG_A2(t + 1, an, 0)
#pragma unroll
    for (int j = 0; j < 4; ++j) {
      bfrag[j][0] = *(const bf16x8*)(Bc + rowB + j * 1024 + c0);
      bfrag[j][1] = *(const bf16x8*)(Bc + rowB + j * 1024 + c1);
    }
    a0 = *(const bf16x8*)(Ac + rowA + c0);
    a1 = *(const bf16x8*)(Ac + rowA + c1);
    asm volatile("s_waitcnt lgkmcnt(0)" ::: "memory");
    __builtin_amdgcn_sched_barrier(0);
    __builtin_amdgcn_s_setprio(1);
#pragma unroll
    for (int j = 0; j < 4; ++j) {
      acc[0][j] = __builtin_amdgcn_mfma_f32_16x16x32_bf16(a0, bfrag[j][0], acc[0][j], 0, 0, 0);
      acc[0][j] = __builtin_amdgcn_mfma_f32_16x16x32_bf16(a1, bfrag[j][1], acc[0][j], 0, 0, 0);
    }
    __builtin_amdgcn_s_setprio(0);
    __builtin_amdgcn_s_barrier();
    __builtin_amdgcn_sched_barrier(0);

    // ---- phase 1: stage A(t+1) p2,p3 | read A[1] | MFMA i=1 ----
    if (pfA) STG_A2(t + 1, an, 2)
    a0 = *(const bf16x8*)(Ac + 1024 + rowA + c0);
    a1 = *(const bf16x8*)(Ac + 1024 + rowA + c1);
    asm volatile("s_waitcnt lgkmcnt(0)" ::: "memory");
    __builtin_amdgcn_sched_barrier(0);
    __builtin_amdgcn_s_setprio(1);
#pragma unroll
    for (int j = 0; j < 4; ++j) {
      acc[1][j] = __builtin_amdgcn_mfma_f32_16x16x32_bf16(a0, bfrag[j][0], acc[1][j], 0, 0, 0);
      acc[1][j] = __builtin_amdgcn_mfma_f32_16x16x32_bf16(a1, bfrag[j][1], acc[1][j], 0, 0, 0);
    }
    __builtin_amdgcn_s_setprio(0);
    __builtin_amdgcn_s_barrier();
    __builtin_amdgcn_sched_barrier(0);

    // ---- phase 2: stage B(t+2) | read A[2] | MFMA i=2 ----
    if (pfB) STG_B(t + 2, bs2)
    a0 = *(const bf16x8*)(Ac + 2048 + rowA + c0);
    a1 = *(const bf16x8*)(Ac + 2048 + rowA + c1);
    asm volatile("s_waitcnt lgkmcnt(0)" ::: "memory");
    __builtin_amdgcn_sched_barrier(0);
    __builtin_amdgcn_s_setprio(1);
#pragma unroll
    for (int j = 0; j < 4; ++j) {
      acc[2][j] = __builtin_amdgcn_mfma_f32_16x16x32_bf16(a0, bfrag[j][0], acc[2][j], 0, 0, 0);
      acc[2][j] = __builtin_amdgcn_mfma_f32_16x16x32_bf16(a1, bfrag[j][1], acc[2][j], 0, 0, 0);
    }
    __builtin_amdgcn_s_setprio(0);
    __builtin_amdgcn_s_barrier();
    __builtin_amdgcn_sched_barrier(0);

    // ---- phase 3: read A[3] | MFMA i=3 ----
    a0 = *(const bf16x8*)(Ac + 3072 + rowA + c0);
    a1 = *(const bf16x8*)(Ac + 3072 + rowA + c1);
    asm volatile("s_waitcnt lgkmcnt(0)" ::: "memory");
    __builtin_amdgcn_sched_barrier(0);
    __builtin_amdgcn_s_setprio(1);
#pragma unroll
    for (int j = 0; j < 4; ++j) {
      acc[3][j] = __builtin_amdgcn_mfma_f32_16x16x32_bf16(a0, bfrag[j][0], acc[3][j], 0, 0, 0);
      acc[3][j] = __builtin_amdgcn_mfma_f32_16x16x32_bf16(a1, bfrag[j][1], acc[3][j], 0, 0, 0);
    }
    __builtin_amdgcn_s_setprio(0);
    __builtin_amdgcn_s_barrier();
    __builtin_amdgcn_sched_barrier(0);

    acur ^= 1;
    int tmp = bcur; bcur = bs1; bs1 = bs2; bs2 = tmp;
  }
#undef STG_A2
#undef STG_B

  // epilogue: D row = 4*hi4 + r (per 16-frag), col = lo
  const int crow = m0 + wm * 64 + 4 * hi4;
  const int ccol = n0 + wn * 64 + lo;
#pragma unroll
  for (int i = 0; i < 4; ++i) {
#pragma unroll
    for (int j = 0; j < 4; ++j) {
#pragma unroll
      for (int r = 0; r < 4; ++r) {
        const int row = crow + i * 16 + r;
        const int col = ccol + j * 16;
        if constexpr (OUT_BF16) {
          ((ushort*)Cout)[(size_t)row * N + col] = f2bf(acc[i][j][r]);
        } else {
          ((float*)Cout)[(size_t)row * N + col] = acc[i][j][r];
        }
      }
    }
  }
}

// ---------------- RoPE + regroup + per-group mean token ----------------
__global__ __launch_bounds__(256) void rope_group(const ushort* __restrict__ qkv,
                                                  const float* __restrict__ fc,
                                                  const float* __restrict__ fs,
                                                  ushort* __restrict__ qg, ushort* __restrict__ kg,
                                                  ushort* __restrict__ vg,
                                                  float* __restrict__ yq, float* __restrict__ yk) {
  int blk = blockIdx.x;              // ((b*16+h)*16+g)
  int g = blk & 15, h = (blk >> 4) & 15, b = blk >> 8;
  int tid = threadIdx.x;
  int d2 = tid & 31, s0 = tid >> 5;
  size_t gbase = (size_t)blk * SS * HS;
  float sq0 = 0, sq1 = 0, sk0 = 0, sk1 = 0, sv0 = 0, sv1 = 0;
#pragma unroll
  for (int it = 0; it < 16; ++it) {
    int s = s0 + 8 * it;
    int t = g * TG + s;
    size_t rowoff = ((size_t)(b * TT + t)) * (3 * CC) + h * HS + 2 * d2;
    float c = fc[t * 32 + d2], sn = fs[t * 32 + d2];
    ushort2 qu = *(const ushort2*)(qkv + rowoff);
    float qa = bf2f(qu.x), qb = bf2f(qu.y);
    float rq0 = qa * c - qb * sn, rq1 = qa * sn + qb * c;
    ushort2 ku = *(const ushort2*)(qkv + rowoff + CC);
    float ka = bf2f(ku.x), kb = bf2f(ku.y);
    float rk0 = ka * c - kb * sn, rk1 = ka * sn + kb * c;
    ushort2 vu = *(const ushort2*)(qkv + rowoff + 2 * CC);
    float v0 = bf2f(vu.x), v1 = bf2f(vu.y);
    *(ushort2*)(qg + gbase + s * HS + 2 * d2) = make_ushort2(f2bf(rq0), f2bf(rq1));
    *(ushort2*)(kg + gbase + s * HS + 2 * d2) = make_ushort2(f2bf(rk0), f2bf(rk1));
    *(ushort2*)(vg + gbase + s * HS + 2 * d2) = vu;
    sq0 += rq0; sq1 += rq1; sk0 += rk0; sk1 += rk1; sv0 += v0; sv1 += v1;
  }
  __shared__ float red[256][6];
  red[tid][0] = sq0; red[tid][1] = sq1; red[tid][2] = sk0;
  red[tid][3] = sk1; red[tid][4] = sv0; red[tid][5] = sv1;
  __syncthreads();
  if (tid < 32) {
    float m[6];
#pragma unroll
    for (int c = 0; c < 6; ++c) {
      float acc = 0;
#pragma unroll
      for (int r = 0; r < 8; ++r) acc += red[r * 32 + tid][c];
      m[c] = acc * (1.0f / 128.0f);
    }
    *(ushort2*)(qg + gbase + 128 * HS + 2 * tid) = make_ushort2(f2bf(m[0]), f2bf(m[1]));
    *(ushort2*)(kg + gbase + 128 * HS + 2 * tid) = make_ushort2(f2bf(m[2]), f2bf(m[3]));
    *(ushort2*)(vg + gbase + 128 * HS + 2 * tid) = make_ushort2(f2bf(m[4]), f2bf(m[5]));
    if (g < 15) {
      size_t yo = ((size_t)(b * 16 + h) * 15 + g) * 64 + 2 * tid;
      yq[yo] = m[0]; yq[yo + 1] = m[1];
      yk[yo] = m[2]; yk[yo + 1] = m[3];
    }
  }
}

// ---------------- causal attention per (b,h,g), S=129, d=64 — MFMA version ----------------
__global__ __launch_bounds__(256) void attn1(const ushort* __restrict__ qg,
                                             const ushort* __restrict__ kg,
                                             const ushort* __restrict__ vg,
                                             ushort* __restrict__ xo, float* __restrict__ attm) {
  __shared__ ushort ks[144][68];
  __shared__ ushort vt[64][148];   // V^T: vt[d][key]
  __shared__ ushort obuf[4][16][68];
  const int blk = blockIdx.x;
  const int g = blk & 15, h = (blk >> 4) & 15, b = blk >> 8;
  const int tid = threadIdx.x;
  const int lane = tid & 63, wv = tid >> 6;
  const int lo = lane & 15, hi = lane >> 4;
  const size_t gbase = (size_t)blk * SS * HS;

  for (int idx = tid; idx < 320; idx += 256) {
    int d = idx / 5, ch = (idx % 5) * 4;
    *(ushort4*)&vt[d][128 + ch] = make_ushort4(0, 0, 0, 0);
  }
  __syncthreads();
  for (int idx = tid; idx < SS * 16; idx += 256) {
    int s = idx >> 4, c = (idx & 15) * 4;
    *(ushort4*)&ks[s][c] = *(const ushort4*)(kg + gbase + s * HS + c);
    ushort4 v4 = *(const ushort4*)(vg + gbase + s * HS + c);
    vt[c][s] = v4.x; vt[c + 1][s] = v4.y; vt[c + 2][s] = v4.z; vt[c + 3][s] = v4.w;
  }
  __syncthreads();

#pragma unroll
  for (int ti = 0; ti < 3; ++ti) {
    const int t = (ti == 0) ? (8 - wv)
                : (ti == 1) ? ((wv == 3) ? 4 : (wv + 1))
                            : ((wv == 3) ? 0 : -1);
    if (t < 0) continue;
    const int q0 = t * 16;

    const ushort* qrow = qg + gbase + (size_t)(q0 + lo) * HS;
    bf16x8 bq[2];
#pragma unroll
    for (int k2 = 0; k2 < 2; ++k2)
      bq[k2] = mk8(*(const ushort4*)(qrow + k2 * 32 + 4 * hi),
                   *(const ushort4*)(qrow + k2 * 32 + 16 + 4 * hi));

    f32x4 sc[9];
#pragma unroll
    for (int n = 0; n < 9; ++n) sc[n] = (f32x4)0.0f;
#pragma unroll
    for (int n = 0; n < 9; ++n) {
      if (n > t) continue;
#pragma unroll
      for (int k2 = 0; k2 < 2; ++k2) {
        bf16x8 ak = mk8(*(const ushort4*)&ks[n * 16 + lo][k2 * 32 + 4 * hi],
                        *(const ushort4*)&ks[n * 16 + lo][k2 * 32 + 16 + 4 * hi]);
        sc[n] = __builtin_amdgcn_mfma_f32_16x16x32_bf16(ak, bq[k2], sc[n], 0, 0, 0);
      }
    }

    const int qi = q0 + lo;
    float mx = -INFINITY;
#pragma unroll
    for (int n = 0; n < 9; ++n) {
      if (n > t) continue;
#pragma unroll
      for (int r = 0; r < 4; ++r) {
        int kj = n * 16 + 4 * hi + r;
        float v = (kj <= qi) ? sc[n][r] * 0.125f : -INFINITY;
        sc[n][r] = v;
        mx = fmaxf(mx, v);
      }
    }
    mx = fmaxf(mx, __shfl_xor(mx, 16));
    mx = fmaxf(mx, __shfl_xor(mx, 32));
    float sum = 0.f;
#pragma unroll
    for (int n = 0; n < 9; ++n) {
      if (n > t) continue;
#pragma unroll
      for (int r = 0; r < 4; ++r) {
        float e = __expf(sc[n][r] - mx);
        sc[n][r] = e;
        sum += e;
      }
    }
    sum += __shfl_xor(sum, 16);
    sum += __shfl_xor(sum, 32);
    const float inv = 1.0f / sum;

    f32x4 oac[4];
#pragma unroll
    for (int m = 0; m < 4; ++m) oac[m] = (f32x4)0.0f;
#pragma unroll
    for (int s2 = 0; s2 < 5; ++s2) {
      if (s2 > (t >> 1)) continue;
      const int kt1ok = (2 * s2 + 1 <= t);
      bf16x8 pb;
#pragma unroll
      for (int e = 0; e < 4; ++e) pb[e] = (short)f2bf(sc[2 * s2][e] * inv);
      if (kt1ok) {
#pragma unroll
        for (int e = 0; e < 4; ++e) pb[e + 4] = (short)f2bf(sc[2 * s2 + 1][e] * inv);
      } else {
#pragma unroll
        for (int e = 0; e < 4; ++e) pb[e + 4] = 0;
      }
#pragma unroll
      for (int m = 0; m < 4; ++m) {
        ushort4 a0 = *(const ushort4*)&vt[m * 16 + lo][32 * s2 + 4 * hi];
        ushort4 a1 = kt1ok ? *(const ushort4*)&vt[m * 16 + lo][32 * s2 + 16 + 4 * hi]
                           : make_ushort4(0, 0, 0, 0);
        oac[m] = __builtin_amdgcn_mfma_f32_16x16x32_bf16(mk8(a0, a1), pb, oac[m], 0, 0, 0);
      }
    }

    if (t < 8) {
#pragma unroll
      for (int m = 0; m < 4; ++m)
#pragma unroll
        for (int r = 0; r < 4; ++r)
          obuf[wv][lo][m * 16 + 4 * hi + r] = f2bf(oac[m][r]);
#pragma unroll
      for (int it = 0; it < 4; ++it) {
        int idx = lane + 64 * it;
        int r = idx >> 4;
        int c4 = (idx & 15) * 4;
        uint2 val = *(const uint2*)&obuf[wv][r][c4];
        int tok = g * TG + t * 16 + r;
        *(uint2*)(xo + ((size_t)(b * TT + tok)) * CC + h * HS + c4) = val;
      }
    } else {
      if (lo == 0) {
#pragma unroll
        for (int m = 0; m < 4; ++m)
#pragma unroll
          for (int r = 0; r < 4; ++r)
            attm[(size_t)blk * 64 + m * 16 + 4 * hi + r] = oac[m][r];
      }
    }
  }
}

// ---------------- second (tiny) causal attention over 15 group-mean tokens ----------------
__global__ __launch_bounds__(64) void attn2(const float* __restrict__ yq,
                                            const float* __restrict__ yk,
                                            const float* __restrict__ attm,
                                            float* __restrict__ yv) {
  __shared__ float qs2[15][64], ks2[15][64], avs[15][64], srow[16];
  int bh = blockIdx.x, lane = threadIdx.x;
  for (int j = 0; j < 15; ++j) {
    qs2[j][lane] = yq[((size_t)bh * 15 + j) * 64 + lane];
    ks2[j][lane] = yk[((size_t)bh * 15 + j) * 64 + lane];
    avs[j][lane] = attm[((size_t)bh * 16 + j) * 64 + lane];
  }
  __syncthreads();
  for (int i = 0; i < 15; ++i) {
    float qv = qs2[i][lane];
    for (int j = 0; j <= i; ++j) {
      float t = qv * ks2[j][lane];
#pragma unroll
      for (int off = 32; off > 0; off >>= 1) t += __shfl_xor(t, off);
      if (lane == 0) srow[j] = t * 0.125f;
    }
    __syncthreads();
    float mx = -INFINITY;
    for (int j = 0; j <= i; ++j) mx = fmaxf(mx, srow[j]);
    float den = 0;
    for (int j = 0; j <= i; ++j) den += __expf(srow[j] - mx);
    float inv = 1.0f / den;
    float o = 0;
    for (int j = 0; j <= i; ++j) o += __expf(srow[j] - mx) * inv * avs[j][lane];
    yv[((size_t)bh * 15 + i) * 64 + lane] = o;
    __syncthreads();
  }
}

extern "C" void kernel_launch(void* const* d_in, const int* in_sizes, int n_in,
                              void* d_out, int out_size, void* d_ws, size_t ws_size,
                              hipStream_t stream) {
  const float* x      = (const float*)d_in[0];
  const float* w_attn = (const float*)d_in[1];
  const float* w_proj = (const float*)d_in[2];
  const float* fc     = (const float*)d_in[3];
  const float* fs     = (const float*)d_in[4];
  float* out = (float*)d_out;

  char* ws = (char*)d_ws;
  ushort* xb   = (ushort*)(ws);               // x bf16; dead after qkv gemm
  ushort* xo   = (ushort*)(ws);               // reuse xb region (attn1 output)
  ushort* wab  = (ushort*)(ws + 16777216);    // dead after qkv gemm
  float*  attm = (float*) (ws + 16777216);    // reuse wab region
  ushort* wpb  = (ushort*)(ws + 23068672);
  ushort* qkv  = (ushort*)(ws + 25165824);    // (B*T) x 3C bf16
  ushort* qg   = (ushort*)(ws + 75497472);    // (B,H,G,129,64) bf16
  ushort* kg   = (ushort*)(ws + 92405760);
  ushort* vg   = (ushort*)(ws + 109314048);   // end 126,222,336

  float* yq = out + 8388608;
  float* yk = out + 8450048;
  float* yv = out + 8511488;

  cvt_f32_bf16<<<2048, 256, 0, stream>>>(x, xb, 8388608 / 4);
  cvt_f32_bf16<<<1024, 256, 0, stream>>>(w_attn, wab, 3145728 / 4);
  cvt_f32_bf16<<<512, 256, 0, stream>>>(w_proj, wpb, 1048576 / 4);
  gemm8p<true><<<768, 512, 0, stream>>>(xb, wab, qkv, 3072, 1024, 24);
  rope_group<<<1024, 256, 0, stream>>>(qkv, fc, fs, qg, kg, vg, yq, yk);
  attn1<<<1024, 256, 0, stream>>>(qg, kg, vg, xo, attm);
  attn2<<<64, 64, 0, stream>>>(yq, yk, attm, yv);
  gemm8p<false><<<256, 512, 0, stream>>>(xo, wpb, out, 1024, 1024, 8);
}

// Round 10
// 210.261 us; speedup vs baseline: 1.0526x; 1.0526x over previous
//
#include <hip/hip_runtime.h>
#include <hip/hip_bf16.h>

#define HS 64
#define NH 16
#define NG 16
#define TT 2048
#define CC 1024
#define BBATCH 4
#define TG 128
#define SS 129   // TG+1

typedef __attribute__((ext_vector_type(8))) short bf16x8;
typedef __attribute__((ext_vector_type(4))) float f32x4;

__device__ __forceinline__ float bf2f(ushort u) {
  return __uint_as_float(((unsigned)u) << 16);
}
__device__ __forceinline__ ushort f2bf(float f) {
  unsigned x = __float_as_uint(f);
  x += 0x7fff + ((x >> 16) & 1);
  return (ushort)(x >> 16);
}
__device__ __forceinline__ bf16x8 mk8(ushort4 a0, ushort4 a1) {
  bf16x8 v;
  v[0] = (short)a0.x; v[1] = (short)a0.y; v[2] = (short)a0.z; v[3] = (short)a0.w;
  v[4] = (short)a1.x; v[5] = (short)a1.y; v[6] = (short)a1.z; v[7] = (short)a1.w;
  return v;
}
__device__ __forceinline__ void load_lds16(const ushort* g, ushort* l) {
  __builtin_amdgcn_global_load_lds((const __attribute__((address_space(1))) unsigned int*)g,
                                   (__attribute__((address_space(3))) unsigned int*)l, 16, 0, 0);
}

// ---------------- fp32 -> bf16 convert ----------------
__global__ void cvt_f32_bf16(const float* __restrict__ src, ushort* __restrict__ dst, int n4) {
  int stride = gridDim.x * blockDim.x;
  for (int i = blockIdx.x * blockDim.x + threadIdx.x; i < n4; i += stride) {
    float4 v = ((const float4*)src)[i];
    ushort4 o;
    o.x = f2bf(v.x); o.y = f2bf(v.y); o.z = f2bf(v.z); o.w = f2bf(v.w);
    ((ushort4*)dst)[i] = o;
  }
}

// ---------------- GEMM mainloop core (128x128 tile, BK=64, global_load_lds) ----------------
// Both A/B frag reads use the same contiguous-k slot permutation -> cancels in MFMA.
#define GEMM_CORE(A_, B_, K_, m0_, n0_)                                            \
  {                                                                                \
    const int rA = tid >> 3, cA = (tid & 7) * 8;                                   \
    for (int k0 = 0; k0 < (K_); k0 += 64) {                                        \
      _Pragma("unroll")                                                            \
      for (int it = 0; it < 4; ++it) {                                             \
        load_lds16((A_) + (size_t)((m0_) + it * 32 + rA) * (K_) + k0 + cA,         \
                   As + it * 2048 + wv * 512);                                     \
        load_lds16((B_) + (size_t)((n0_) + it * 32 + rA) * (K_) + k0 + cA,         \
                   Bs + it * 2048 + wv * 512);                                     \
      }                                                                            \
      __syncthreads();                                                             \
      _Pragma("unroll")                                                            \
      for (int kk = 0; kk < 64; kk += 32) {                                        \
        bf16x8 af[4], bfr[4];                                                      \
        _Pragma("unroll")                                                          \
        for (int i = 0; i < 4; ++i)                                                \
          af[i] = *(const bf16x8*)(As + (wr * 64 + i * 16 + lo) * 64 + kk + 8 * hi); \
        _Pragma("unroll")                                                          \
        for (int j = 0; j < 4; ++j)                                                \
          bfr[j] = *(const bf16x8*)(Bs + (wc * 64 + j * 16 + lo) * 64 + kk + 8 * hi); \
        _Pragma("unroll")                                                          \
        for (int i = 0; i < 4; ++i)                                                \
          _Pragma("unroll")                                                        \
          for (int j = 0; j < 4; ++j)                                              \
            acc[i][j] = __builtin_amdgcn_mfma_f32_16x16x32_bf16(af[i], bfr[j], acc[i][j], 0, 0, 0); \
      }                                                                            \
      __syncthreads();                                                             \
    }                                                                              \
  }

// ---------------- plain bf16 GEMM with chunked XCD swizzle ----------------
// C[m][n] = sum_k A[m][k] * Bw[n][k]
template <bool OUT_BF16>
__global__ __launch_bounds__(256) void gemm_bt(const ushort* __restrict__ A,
                                               const ushort* __restrict__ Bw,
                                               void* __restrict__ Cout,
                                               int M, int N, int K) {
  __shared__ ushort As[128 * 64];
  __shared__ ushort Bs[128 * 64];
  // chunked XCD swizzle: each XCD gets a contiguous 1/8 of the grid (nwg % 8 == 0)
  const int id = blockIdx.x + gridDim.x * blockIdx.y;
  const int chunk = (gridDim.x * gridDim.y) >> 3;
  const int nid = (id & 7) * chunk + (id >> 3);
  const int m0 = (nid / gridDim.x) * 128;
  const int n0 = (nid % gridDim.x) * 128;
  const int tid = threadIdx.x;
  const int lane = tid & 63;
  const int wv = tid >> 6;
  const int wr = wv >> 1, wc = wv & 1;
  const int lo = lane & 15, hi = lane >> 4;

  f32x4 acc[4][4];
#pragma unroll
  for (int i = 0; i < 4; ++i)
#pragma unroll
    for (int j = 0; j < 4; ++j) acc[i][j] = (f32x4)0.0f;

  GEMM_CORE(A, Bw, K, m0, n0)

#pragma unroll
  for (int i = 0; i < 4; ++i) {
    int row = m0 + wr * 64 + i * 16 + 4 * hi;
#pragma unroll
    for (int j = 0; j < 4; ++j) {
      int col = n0 + wc * 64 + j * 16 + lo;
#pragma unroll
      for (int r = 0; r < 4; ++r) {
        float v = acc[i][j][r];
        if constexpr (OUT_BF16) {
          ((ushort*)Cout)[(size_t)(row + r) * N + col] = f2bf(v);
        } else {
          ((float*)Cout)[(size_t)(row + r) * N + col] = v;
        }
      }
    }
  }
}

// ---------------- RoPE + regroup + per-group mean token ----------------
__global__ __launch_bounds__(256) void rope_group(const ushort* __restrict__ qkv,
                                                  const float* __restrict__ fc,
                                                  const float* __restrict__ fs,
                                                  ushort* __restrict__ qg, ushort* __restrict__ kg,
                                                  ushort* __restrict__ vg,
                                                  float* __restrict__ yq, float* __restrict__ yk) {
  int blk = blockIdx.x;              // ((b*16+h)*16+g)
  int g = blk & 15, h = (blk >> 4) & 15, b = blk >> 8;
  int tid = threadIdx.x;
  int d2 = tid & 31, s0 = tid >> 5;
  size_t gbase = (size_t)blk * SS * HS;
  float sq0 = 0, sq1 = 0, sk0 = 0, sk1 = 0, sv0 = 0, sv1 = 0;
#pragma unroll
  for (int it = 0; it < 16; ++it) {
    int s = s0 + 8 * it;
    int t = g * TG + s;
    size_t rowoff = ((size_t)(b * TT + t)) * (3 * CC) + h * HS + 2 * d2;
    float c = fc[t * 32 + d2], sn = fs[t * 32 + d2];
    ushort2 qu = *(const ushort2*)(qkv + rowoff);
    float qa = bf2f(qu.x), qb = bf2f(qu.y);
    float rq0 = qa * c - qb * sn, rq1 = qa * sn + qb * c;
    ushort2 ku = *(const ushort2*)(qkv + rowoff + CC);
    float ka = bf2f(ku.x), kb = bf2f(ku.y);
    float rk0 = ka * c - kb * sn, rk1 = ka * sn + kb * c;
    ushort2 vu = *(const ushort2*)(qkv + rowoff + 2 * CC);
    float v0 = bf2f(vu.x), v1 = bf2f(vu.y);
    *(ushort2*)(qg + gbase + s * HS + 2 * d2) = make_ushort2(f2bf(rq0), f2bf(rq1));
    *(ushort2*)(kg + gbase + s * HS + 2 * d2) = make_ushort2(f2bf(rk0), f2bf(rk1));
    *(ushort2*)(vg + gbase + s * HS + 2 * d2) = vu;
    sq0 += rq0; sq1 += rq1; sk0 += rk0; sk1 += rk1; sv0 += v0; sv1 += v1;
  }
  __shared__ float red[256][6];
  red[tid][0] = sq0; red[tid][1] = sq1; red[tid][2] = sk0;
  red[tid][3] = sk1; red[tid][4] = sv0; red[tid][5] = sv1;
  __syncthreads();
  if (tid < 32) {
    float m[6];
#pragma unroll
    for (int c = 0; c < 6; ++c) {
      float acc = 0;
#pragma unroll
      for (int r = 0; r < 8; ++r) acc += red[r * 32 + tid][c];
      m[c] = acc * (1.0f / 128.0f);
    }
    *(ushort2*)(qg + gbase + 128 * HS + 2 * tid) = make_ushort2(f2bf(m[0]), f2bf(m[1]));
    *(ushort2*)(kg + gbase + 128 * HS + 2 * tid) = make_ushort2(f2bf(m[2]), f2bf(m[3]));
    *(ushort2*)(vg + gbase + 128 * HS + 2 * tid) = make_ushort2(f2bf(m[4]), f2bf(m[5]));
    if (g < 15) {
      size_t yo = ((size_t)(b * 16 + h) * 15 + g) * 64 + 2 * tid;
      yq[yo] = m[0]; yq[yo + 1] = m[1];
      yk[yo] = m[2]; yk[yo + 1] = m[3];
    }
  }
}

// ---------------- causal attention per (b,h,g), S=129, d=64 — MFMA version ----------------
__global__ __launch_bounds__(256) void attn1(const ushort* __restrict__ qg,
                                             const ushort* __restrict__ kg,
                                             const ushort* __restrict__ vg,
                                             ushort* __restrict__ xo, float* __restrict__ attm) {
  __shared__ ushort ks[144][68];
  __shared__ ushort vt[64][148];   // V^T: vt[d][key]
  __shared__ ushort obuf[4][16][68];
  const int blk = blockIdx.x;
  const int g = blk & 15, h = (blk >> 4) & 15, b = blk >> 8;
  const int tid = threadIdx.x;
  const int lane = tid & 63, wv = tid >> 6;
  const int lo = lane & 15, hi = lane >> 4;
  const size_t gbase = (size_t)blk * SS * HS;

  for (int idx = tid; idx < 320; idx += 256) {
    int d = idx / 5, ch = (idx % 5) * 4;
    *(ushort4*)&vt[d][128 + ch] = make_ushort4(0, 0, 0, 0);
  }
  __syncthreads();
  for (int idx = tid; idx < SS * 16; idx += 256) {
    int s = idx >> 4, c = (idx & 15) * 4;
    *(ushort4*)&ks[s][c] = *(const ushort4*)(kg + gbase + s * HS + c);
    ushort4 v4 = *(const ushort4*)(vg + gbase + s * HS + c);
    vt[c][s] = v4.x; vt[c + 1][s] = v4.y; vt[c + 2][s] = v4.z; vt[c + 3][s] = v4.w;
  }
  __syncthreads();

#pragma unroll
  for (int ti = 0; ti < 3; ++ti) {
    const int t = (ti == 0) ? (8 - wv)
                : (ti == 1) ? ((wv == 3) ? 4 : (wv + 1))
                            : ((wv == 3) ? 0 : -1);
    if (t < 0) continue;
    const int q0 = t * 16;

    const ushort* qrow = qg + gbase + (size_t)(q0 + lo) * HS;
    bf16x8 bq[2];
#pragma unroll
    for (int k2 = 0; k2 < 2; ++k2)
      bq[k2] = mk8(*(const ushort4*)(qrow + k2 * 32 + 4 * hi),
                   *(const ushort4*)(qrow + k2 * 32 + 16 + 4 * hi));

    f32x4 sc[9];
#pragma unroll
    for (int n = 0; n < 9; ++n) sc[n] = (f32x4)0.0f;
#pragma unroll
    for (int n = 0; n < 9; ++n) {
      if (n > t) continue;
#pragma unroll
      for (int k2 = 0; k2 < 2; ++k2) {
        bf16x8 ak = mk8(*(const ushort4*)&ks[n * 16 + lo][k2 * 32 + 4 * hi],
                        *(const ushort4*)&ks[n * 16 + lo][k2 * 32 + 16 + 4 * hi]);
        sc[n] = __builtin_amdgcn_mfma_f32_16x16x32_bf16(ak, bq[k2], sc[n], 0, 0, 0);
      }
    }

    const int qi = q0 + lo;
    float mx = -INFINITY;
#pragma unroll
    for (int n = 0; n < 9; ++n) {
      if (n > t) continue;
#pragma unroll
      for (int r = 0; r < 4; ++r) {
        int kj = n * 16 + 4 * hi + r;
        float v = (kj <= qi) ? sc[n][r] * 0.125f : -INFINITY;
        sc[n][r] = v;
        mx = fmaxf(mx, v);
      }
    }
    mx = fmaxf(mx, __shfl_xor(mx, 16));
    mx = fmaxf(mx, __shfl_xor(mx, 32));
    float sum = 0.f;
#pragma unroll
    for (int n = 0; n < 9; ++n) {
      if (n > t) continue;
#pragma unroll
      for (int r = 0; r < 4; ++r) {
        float e = __expf(sc[n][r] - mx);
        sc[n][r] = e;
        sum += e;
      }
    }
    sum += __shfl_xor(sum, 16);
    sum += __shfl_xor(sum, 32);
    const float inv = 1.0f / sum;

    f32x4 oac[4];
#pragma unroll
    for (int m = 0; m < 4; ++m) oac[m] = (f32x4)0.0f;
#pragma unroll
    for (int s2 = 0; s2 < 5; ++s2) {
      if (s2 > (t >> 1)) continue;
      const int kt1ok = (2 * s2 + 1 <= t);
      bf16x8 pb;
#pragma unroll
      for (int e = 0; e < 4; ++e) pb[e] = (short)f2bf(sc[2 * s2][e] * inv);
      if (kt1ok) {
#pragma unroll
        for (int e = 0; e < 4; ++e) pb[e + 4] = (short)f2bf(sc[2 * s2 + 1][e] * inv);
      } else {
#pragma unroll
        for (int e = 0; e < 4; ++e) pb[e + 4] = 0;
      }
#pragma unroll
      for (int m = 0; m < 4; ++m) {
        ushort4 a0 = *(const ushort4*)&vt[m * 16 + lo][32 * s2 + 4 * hi];
        ushort4 a1 = kt1ok ? *(const ushort4*)&vt[m * 16 + lo][32 * s2 + 16 + 4 * hi]
                           : make_ushort4(0, 0, 0, 0);
        oac[m] = __builtin_amdgcn_mfma_f32_16x16x32_bf16(mk8(a0, a1), pb, oac[m], 0, 0, 0);
      }
    }

    if (t < 8) {
#pragma unroll
      for (int m = 0; m < 4; ++m)
#pragma unroll
        for (int r = 0; r < 4; ++r)
          obuf[wv][lo][m * 16 + 4 * hi + r] = f2bf(oac[m][r]);
#pragma unroll
      for (int it = 0; it < 4; ++it) {
        int idx = lane + 64 * it;
        int r = idx >> 4;
        int c4 = (idx & 15) * 4;
        uint2 val = *(const uint2*)&obuf[wv][r][c4];
        int tok = g * TG + t * 16 + r;
        *(uint2*)(xo + ((size_t)(b * TT + tok)) * CC + h * HS + c4) = val;
      }
    } else {
      if (lo == 0) {
#pragma unroll
        for (int m = 0; m < 4; ++m)
#pragma unroll
          for (int r = 0; r < 4; ++r)
            attm[(size_t)blk * 64 + m * 16 + 4 * hi + r] = oac[m][r];
      }
    }
  }
}

// ---------------- second (tiny) causal attention over 15 group-mean tokens ----------------
__global__ __launch_bounds__(64) void attn2(const float* __restrict__ yq,
                                            const float* __restrict__ yk,
                                            const float* __restrict__ attm,
                                            float* __restrict__ yv) {
  __shared__ float qs2[15][64], ks2[15][64], avs[15][64], srow[16];
  int bh = blockIdx.x, lane = threadIdx.x;
  for (int j = 0; j < 15; ++j) {
    qs2[j][lane] = yq[((size_t)bh * 15 + j) * 64 + lane];
    ks2[j][lane] = yk[((size_t)bh * 15 + j) * 64 + lane];
    avs[j][lane] = attm[((size_t)bh * 16 + j) * 64 + lane];
  }
  __syncthreads();
  for (int i = 0; i < 15; ++i) {
    float qv = qs2[i][lane];
    for (int j = 0; j <= i; ++j) {
      float t = qv * ks2[j][lane];
#pragma unroll
      for (int off = 32; off > 0; off >>= 1) t += __shfl_xor(t, off);
      if (lane == 0) srow[j] = t * 0.125f;
    }
    __syncthreads();
    float mx = -INFINITY;
    for (int j = 0; j <= i; ++j) mx = fmaxf(mx, srow[j]);
    float den = 0;
    for (int j = 0; j <= i; ++j) den += __expf(srow[j] - mx);
    float inv = 1.0f / den;
    float o = 0;
    for (int j = 0; j <= i; ++j) o += __expf(srow[j] - mx) * inv * avs[j][lane];
    yv[((size_t)bh * 15 + i) * 64 + lane] = o;
    __syncthreads();
  }
}

extern "C" void kernel_launch(void* const* d_in, const int* in_sizes, int n_in,
                              void* d_out, int out_size, void* d_ws, size_t ws_size,
                              hipStream_t stream) {
  const float* x      = (const float*)d_in[0];
  const float* w_attn = (const float*)d_in[1];
  const float* w_proj = (const float*)d_in[2];
  const float* fc     = (const float*)d_in[3];
  const float* fs     = (const float*)d_in[4];
  float* out = (float*)d_out;

  char* ws = (char*)d_ws;
  ushort* xb   = (ushort*)(ws);               // x bf16; dead after qkv gemm
  ushort* xo   = (ushort*)(ws);               // reuse xb region (attn1 output)
  ushort* wab  = (ushort*)(ws + 16777216);    // dead after qkv gemm
  float*  attm = (float*) (ws + 16777216);    // reuse wab region
  ushort* wpb  = (ushort*)(ws + 23068672);
  ushort* qkv  = (ushort*)(ws + 25165824);    // (B*T) x 3C bf16
  ushort* qg   = (ushort*)(ws + 75497472);    // (B,H,G,129,64) bf16
  ushort* kg   = (ushort*)(ws + 92405760);
  ushort* vg   = (ushort*)(ws + 109314048);   // end 126,222,336

  float* yq = out + 8388608;
  float* yk = out + 8450048;
  float* yv = out + 8511488;

  cvt_f32_bf16<<<2048, 256, 0, stream>>>(x, xb, 8388608 / 4);
  cvt_f32_bf16<<<1024, 256, 0, stream>>>(w_attn, wab, 3145728 / 4);
  cvt_f32_bf16<<<512, 256, 0, stream>>>(w_proj, wpb, 1048576 / 4);
  gemm_bt<true><<<dim3(24, 64), 256, 0, stream>>>(xb, wab, qkv, 8192, 3072, 1024);
  rope_group<<<1024, 256, 0, stream>>>(qkv, fc, fs, qg, kg, vg, yq, yk);
  attn1<<<1024, 256, 0, stream>>>(qg, kg, vg, xo, attm);
  attn2<<<64, 64, 0, stream>>>(yq, yk, attm, yv);
  gemm_bt<false><<<dim3(8, 64), 256, 0, stream>>>(xo, wpb, out, 8192, 1024, 1024);
}

// Round 11
// 186.544 us; speedup vs baseline: 1.1864x; 1.1271x over previous
//
#include <hip/hip_runtime.h>
#include <hip/hip_bf16.h>

#define HS 64
#define NH 16
#define NG 16
#define TT 2048
#define CC 1024
#define BBATCH 4
#define TG 128
#define SS 129   // TG+1

typedef __attribute__((ext_vector_type(8))) short bf16x8;
typedef __attribute__((ext_vector_type(4))) float f32x4;

__device__ __forceinline__ float bf2f(ushort u) {
  return __uint_as_float(((unsigned)u) << 16);
}
__device__ __forceinline__ ushort f2bf(float f) {
  unsigned x = __float_as_uint(f);
  x += 0x7fff + ((x >> 16) & 1);
  return (ushort)(x >> 16);
}
__device__ __forceinline__ bf16x8 mk8(ushort4 a0, ushort4 a1) {
  bf16x8 v;
  v[0] = (short)a0.x; v[1] = (short)a0.y; v[2] = (short)a0.z; v[3] = (short)a0.w;
  v[4] = (short)a1.x; v[5] = (short)a1.y; v[6] = (short)a1.z; v[7] = (short)a1.w;
  return v;
}

// ---------------- fused fp32 -> bf16 convert (x, w_attn, w_proj in one launch) ----------------
__global__ void cvt3(const float* __restrict__ x, const float* __restrict__ wa,
                     const float* __restrict__ wp, ushort* __restrict__ xb,
                     ushort* __restrict__ wab, ushort* __restrict__ wpb) {
  const int stride = gridDim.x * blockDim.x;
  for (int i = blockIdx.x * blockDim.x + threadIdx.x; i < 3145728; i += stride) {
    const float* src; ushort* dst; int off;
    if (i < 2097152) { src = x; dst = xb; off = i; }
    else if (i < 2883584) { src = wa; dst = wab; off = i - 2097152; }
    else { src = wp; dst = wpb; off = i - 2883584; }
    float4 v = ((const float4*)src)[off];
    ushort4 o;
    o.x = f2bf(v.x); o.y = f2bf(v.y); o.z = f2bf(v.z); o.w = f2bf(v.w);
    ((ushort4*)dst)[off] = o;
  }
}

// ---------------- bf16 GEMM (r2-proven reg-staged, pad-68):  C = A * Bw^T ----------------
template <bool OUT_BF16>
__global__ __launch_bounds__(256) void gemm_bt(const ushort* __restrict__ A,
                                               const ushort* __restrict__ Bw,
                                               void* __restrict__ Cout,
                                               int M, int N, int K) {
  __shared__ ushort As[128][68];
  __shared__ ushort Bs[128][68];
  const int m0 = blockIdx.y * 128;
  const int n0 = blockIdx.x * 128;
  const int tid = threadIdx.x;
  const int lane = tid & 63;
  const int wv = tid >> 6;
  const int wr = wv >> 1, wc = wv & 1;
  const int lo = lane & 15, hi = lane >> 4;

  f32x4 acc[4][4];
#pragma unroll
  for (int i = 0; i < 4; ++i)
#pragma unroll
    for (int j = 0; j < 4; ++j) acc[i][j] = (f32x4)0.0f;

  for (int k0 = 0; k0 < K; k0 += 64) {
    __syncthreads();
#pragma unroll
    for (int t = 0; t < 4; ++t) {
      int c = tid + 256 * t;
      int row = c >> 3, cc = c & 7;
      uint4 va = *(const uint4*)(A + (size_t)(m0 + row) * K + k0 + cc * 8);
      *(uint2*)&As[row][cc * 8]     = make_uint2(va.x, va.y);
      *(uint2*)&As[row][cc * 8 + 4] = make_uint2(va.z, va.w);
      uint4 vb = *(const uint4*)(Bw + (size_t)(n0 + row) * K + k0 + cc * 8);
      *(uint2*)&Bs[row][cc * 8]     = make_uint2(vb.x, vb.y);
      *(uint2*)&Bs[row][cc * 8 + 4] = make_uint2(vb.z, vb.w);
    }
    __syncthreads();
#pragma unroll
    for (int kk = 0; kk < 64; kk += 32) {
      bf16x8 af[4], bfr[4];
#pragma unroll
      for (int i = 0; i < 4; ++i) {
        int r = wr * 64 + i * 16 + lo;
        af[i] = mk8(*(const ushort4*)&As[r][kk + 4 * hi],
                    *(const ushort4*)&As[r][kk + 16 + 4 * hi]);
      }
#pragma unroll
      for (int j = 0; j < 4; ++j) {
        int r = wc * 64 + j * 16 + lo;
        bfr[j] = mk8(*(const ushort4*)&Bs[r][kk + 4 * hi],
                     *(const ushort4*)&Bs[r][kk + 16 + 4 * hi]);
      }
#pragma unroll
      for (int i = 0; i < 4; ++i)
#pragma unroll
        for (int j = 0; j < 4; ++j)
          acc[i][j] = __builtin_amdgcn_mfma_f32_16x16x32_bf16(af[i], bfr[j], acc[i][j], 0, 0, 0);
    }
  }
#pragma unroll
  for (int i = 0; i < 4; ++i) {
    int row = m0 + wr * 64 + i * 16 + 4 * hi;
#pragma unroll
    for (int j = 0; j < 4; ++j) {
      int col = n0 + wc * 64 + j * 16 + lo;
#pragma unroll
      for (int r = 0; r < 4; ++r) {
        float v = acc[i][j][r];
        if constexpr (OUT_BF16) {
          ((ushort*)Cout)[(size_t)(row + r) * N + col] = f2bf(v);
        } else {
          ((float*)Cout)[(size_t)(row + r) * N + col] = v;
        }
      }
    }
  }
}

// ---------------- fused RoPE + mean + causal attention per (b,h,g) ----------------
// Stages raw q/k/v straight from qkv, ropes in-LDS (fp32), computes the group mean
// token in-block (-> row 128 + yq/yk), then runs the swapped-operand MFMA attention.
__global__ __launch_bounds__(256) void attn1f(const ushort* __restrict__ qkv,
                                              const float* __restrict__ fc,
                                              const float* __restrict__ fs,
                                              ushort* __restrict__ xo, float* __restrict__ attm,
                                              float* __restrict__ yq, float* __restrict__ yk) {
  __shared__ ushort qs[144][68];
  __shared__ ushort ks[144][68];
  __shared__ ushort vt[64][148];   // V^T: vt[d][key]
  __shared__ ushort obuf[4][16][68];
  __shared__ float red[256][6];
  const int blk = blockIdx.x;
  const int g = blk & 15, h = (blk >> 4) & 15, b = blk >> 8;
  const int tid = threadIdx.x;
  const int lane = tid & 63, wv = tid >> 6;
  const int lo = lane & 15, hi = lane >> 4;

  // phase A: zero vt pad cols 128..147 (PV touches them with pb==0; must be finite)
  for (int idx = tid; idx < 320; idx += 256) {
    int d = idx / 5, ch = (idx % 5) * 4;
    *(ushort4*)&vt[d][128 + ch] = make_ushort4(0, 0, 0, 0);
  }
  // stage raw q/k/v rows 0..127 from qkv (128 B contiguous per row-part)
  const size_t rowbase = (size_t)(b * TT + g * TG) * (3 * CC) + h * HS;
  for (int idx = tid; idx < 3072; idx += 256) {
    int part = idx >> 10, rem = idx & 1023, s = rem >> 3, c8 = (rem & 7) * 8;
    uint4 w = *(const uint4*)(qkv + rowbase + (size_t)s * (3 * CC) + part * CC + c8);
    if (part == 0) {
      *(uint4*)&qs[s][c8] = w;
    } else if (part == 1) {
      *(uint4*)&ks[s][c8] = w;
    } else {
      ushort e[8];
      *(uint4*)e = w;
#pragma unroll
      for (int j = 0; j < 8; ++j) vt[c8 + j][s] = e[j];
    }
  }
  __syncthreads();

  // phase B: rope q/k in fp32 (write back bf16) + fp32 column sums for the mean
  {
    const int d2 = tid & 31, sg = tid >> 5;
    float sq0 = 0, sq1 = 0, sk0 = 0, sk1 = 0, sv0 = 0, sv1 = 0;
#pragma unroll
    for (int it = 0; it < 16; ++it) {
      int s = sg + 8 * it;
      int ts = g * TG + s;
      float c = fc[ts * 32 + d2], sn = fs[ts * 32 + d2];
      ushort2 qu = *(const ushort2*)&qs[s][2 * d2];
      float qa = bf2f(qu.x), qb = bf2f(qu.y);
      float rq0 = qa * c - qb * sn, rq1 = qa * sn + qb * c;
      *(ushort2*)&qs[s][2 * d2] = make_ushort2(f2bf(rq0), f2bf(rq1));
      ushort2 ku = *(const ushort2*)&ks[s][2 * d2];
      float ka = bf2f(ku.x), kb = bf2f(ku.y);
      float rk0 = ka * c - kb * sn, rk1 = ka * sn + kb * c;
      *(ushort2*)&ks[s][2 * d2] = make_ushort2(f2bf(rk0), f2bf(rk1));
      float v0 = bf2f(vt[2 * d2][s]), v1 = bf2f(vt[2 * d2 + 1][s]);
      sq0 += rq0; sq1 += rq1; sk0 += rk0; sk1 += rk1; sv0 += v0; sv1 += v1;
    }
    red[tid][0] = sq0; red[tid][1] = sq1; red[tid][2] = sk0;
    red[tid][3] = sk1; red[tid][4] = sv0; red[tid][5] = sv1;
  }
  __syncthreads();
  if (tid < 32) {
    float m[6];
#pragma unroll
    for (int c = 0; c < 6; ++c) {
      float acc = 0;
#pragma unroll
      for (int r = 0; r < 8; ++r) acc += red[r * 32 + tid][c];
      m[c] = acc * (1.0f / 128.0f);
    }
    *(ushort2*)&qs[128][2 * tid] = make_ushort2(f2bf(m[0]), f2bf(m[1]));
    *(ushort2*)&ks[128][2 * tid] = make_ushort2(f2bf(m[2]), f2bf(m[3]));
    vt[2 * tid][128] = f2bf(m[4]);
    vt[2 * tid + 1][128] = f2bf(m[5]);
    if (g < 15) {
      size_t yo = ((size_t)(b * 16 + h) * 15 + g) * 64 + 2 * tid;
      yq[yo] = m[0]; yq[yo + 1] = m[1];
      yk[yo] = m[2]; yk[yo + 1] = m[3];
    }
  }
  __syncthreads();

  // phase C: attention (stale qs/ks rows 129..143 contained by masking / discarded cols)
#pragma unroll
  for (int ti = 0; ti < 3; ++ti) {
    const int t = (ti == 0) ? (8 - wv)
                : (ti == 1) ? ((wv == 3) ? 4 : (wv + 1))
                            : ((wv == 3) ? 0 : -1);
    if (t < 0) continue;
    const int q0 = t * 16;

    bf16x8 bq[2];
#pragma unroll
    for (int k2 = 0; k2 < 2; ++k2)
      bq[k2] = mk8(*(const ushort4*)&qs[q0 + lo][k2 * 32 + 4 * hi],
                   *(const ushort4*)&qs[q0 + lo][k2 * 32 + 16 + 4 * hi]);

    f32x4 sc[9];
#pragma unroll
    for (int n = 0; n < 9; ++n) sc[n] = (f32x4)0.0f;
#pragma unroll
    for (int n = 0; n < 9; ++n) {
      if (n > t) continue;
#pragma unroll
      for (int k2 = 0; k2 < 2; ++k2) {
        bf16x8 ak = mk8(*(const ushort4*)&ks[n * 16 + lo][k2 * 32 + 4 * hi],
                        *(const ushort4*)&ks[n * 16 + lo][k2 * 32 + 16 + 4 * hi]);
        sc[n] = __builtin_amdgcn_mfma_f32_16x16x32_bf16(ak, bq[k2], sc[n], 0, 0, 0);
      }
    }

    const int qi = q0 + lo;
    float mx = -INFINITY;
#pragma unroll
    for (int n = 0; n < 9; ++n) {
      if (n > t) continue;
#pragma unroll
      for (int r = 0; r < 4; ++r) {
        int kj = n * 16 + 4 * hi + r;
        float v = (kj <= qi) ? sc[n][r] * 0.125f : -INFINITY;
        sc[n][r] = v;
        mx = fmaxf(mx, v);
      }
    }
    mx = fmaxf(mx, __shfl_xor(mx, 16));
    mx = fmaxf(mx, __shfl_xor(mx, 32));
    float sum = 0.f;
#pragma unroll
    for (int n = 0; n < 9; ++n) {
      if (n > t) continue;
#pragma unroll
      for (int r = 0; r < 4; ++r) {
        float e = __expf(sc[n][r] - mx);
        sc[n][r] = e;
        sum += e;
      }
    }
    sum += __shfl_xor(sum, 16);
    sum += __shfl_xor(sum, 32);
    const float inv = 1.0f / sum;

    f32x4 oac[4];
#pragma unroll
    for (int m = 0; m < 4; ++m) oac[m] = (f32x4)0.0f;
#pragma unroll
    for (int s2 = 0; s2 < 5; ++s2) {
      if (s2 > (t >> 1)) continue;
      const int kt1ok = (2 * s2 + 1 <= t);
      bf16x8 pb;
#pragma unroll
      for (int e = 0; e < 4; ++e) pb[e] = (short)f2bf(sc[2 * s2][e] * inv);
      if (kt1ok) {
#pragma unroll
        for (int e = 0; e < 4; ++e) pb[e + 4] = (short)f2bf(sc[2 * s2 + 1][e] * inv);
      } else {
#pragma unroll
        for (int e = 0; e < 4; ++e) pb[e + 4] = 0;
      }
#pragma unroll
      for (int m = 0; m < 4; ++m) {
        ushort4 a0 = *(const ushort4*)&vt[m * 16 + lo][32 * s2 + 4 * hi];
        ushort4 a1 = kt1ok ? *(const ushort4*)&vt[m * 16 + lo][32 * s2 + 16 + 4 * hi]
                           : make_ushort4(0, 0, 0, 0);
        oac[m] = __builtin_amdgcn_mfma_f32_16x16x32_bf16(mk8(a0, a1), pb, oac[m], 0, 0, 0);
      }
    }

    if (t < 8) {
#pragma unroll
      for (int m = 0; m < 4; ++m)
#pragma unroll
        for (int r = 0; r < 4; ++r)
          obuf[wv][lo][m * 16 + 4 * hi + r] = f2bf(oac[m][r]);
#pragma unroll
      for (int it = 0; it < 4; ++it) {
        int idx = lane + 64 * it;
        int r = idx >> 4;
        int c4 = (idx & 15) * 4;
        uint2 val = *(const uint2*)&obuf[wv][r][c4];
        int tok = g * TG + t * 16 + r;
        *(uint2*)(xo + ((size_t)(b * TT + tok)) * CC + h * HS + c4) = val;
      }
    } else {
      if (lo == 0) {
#pragma unroll
        for (int m = 0; m < 4; ++m)
#pragma unroll
          for (int r = 0; r < 4; ++r)
            attm[(size_t)blk * 64 + m * 16 + 4 * hi + r] = oac[m][r];
      }
    }
  }
}

// ---------------- second (tiny) causal attention over 15 group-mean tokens ----------------
__global__ __launch_bounds__(64) void attn2(const float* __restrict__ yq,
                                            const float* __restrict__ yk,
                                            const float* __restrict__ attm,
                                            float* __restrict__ yv) {
  __shared__ float qs2[15][64], ks2[15][64], avs[15][64], srow[16];
  int bh = blockIdx.x, lane = threadIdx.x;
  for (int j = 0; j < 15; ++j) {
    qs2[j][lane] = yq[((size_t)bh * 15 + j) * 64 + lane];
    ks2[j][lane] = yk[((size_t)bh * 15 + j) * 64 + lane];
    avs[j][lane] = attm[((size_t)bh * 16 + j) * 64 + lane];
  }
  __syncthreads();
  for (int i = 0; i < 15; ++i) {
    float qv = qs2[i][lane];
    for (int j = 0; j <= i; ++j) {
      float t = qv * ks2[j][lane];
#pragma unroll
      for (int off = 32; off > 0; off >>= 1) t += __shfl_xor(t, off);
      if (lane == 0) srow[j] = t * 0.125f;
    }
    __syncthreads();
    float mx = -INFINITY;
    for (int j = 0; j <= i; ++j) mx = fmaxf(mx, srow[j]);
    float den = 0;
    for (int j = 0; j <= i; ++j) den += __expf(srow[j] - mx);
    float inv = 1.0f / den;
    float o = 0;
    for (int j = 0; j <= i; ++j) o += __expf(srow[j] - mx) * inv * avs[j][lane];
    yv[((size_t)bh * 15 + i) * 64 + lane] = o;
    __syncthreads();
  }
}

extern "C" void kernel_launch(void* const* d_in, const int* in_sizes, int n_in,
                              void* d_out, int out_size, void* d_ws, size_t ws_size,
                              hipStream_t stream) {
  const float* x      = (const float*)d_in[0];
  const float* w_attn = (const float*)d_in[1];
  const float* w_proj = (const float*)d_in[2];
  const float* fc     = (const float*)d_in[3];
  const float* fs     = (const float*)d_in[4];
  float* out = (float*)d_out;

  char* ws = (char*)d_ws;
  ushort* xb   = (ushort*)(ws);               // x bf16; dead after qkv gemm
  ushort* xo   = (ushort*)(ws);               // reuse xb region (attn1f output)
  ushort* wab  = (ushort*)(ws + 16777216);    // dead after qkv gemm
  float*  attm = (float*) (ws + 16777216);    // reuse wab region
  ushort* wpb  = (ushort*)(ws + 23068672);
  ushort* qkv  = (ushort*)(ws + 25165824);    // (B*T) x 3C bf16 -> end 75,497,472

  float* yq = out + 8388608;
  float* yk = out + 8450048;
  float* yv = out + 8511488;

  cvt3<<<2048, 256, 0, stream>>>(x, w_attn, w_proj, xb, wab, wpb);
  gemm_bt<true><<<dim3(24, 64), 256, 0, stream>>>(xb, wab, qkv, 8192, 3072, 1024);
  attn1f<<<1024, 256, 0, stream>>>(qkv, fc, fs, xo, attm, yq, yk);
  attn2<<<64, 64, 0, stream>>>(yq, yk, attm, yv);
  gemm_bt<false><<<dim3(8, 64), 256, 0, stream>>>(xo, wpb, out, 8192, 1024, 1024);
}

// Round 13
// 181.789 us; speedup vs baseline: 1.2175x; 1.0262x over previous
//
#include <hip/hip_runtime.h>
#include <hip/hip_bf16.h>

#define HS 64
#define NH 16
#define NG 16
#define TT 2048
#define CC 1024
#define BBATCH 4
#define TG 128
#define SS 129   // TG+1

typedef __attribute__((ext_vector_type(8))) short bf16x8;
typedef __attribute__((ext_vector_type(4))) float f32x4;

__device__ __forceinline__ float bf2f(ushort u) {
  return __uint_as_float(((unsigned)u) << 16);
}
__device__ __forceinline__ ushort f2bf(float f) {
  unsigned x = __float_as_uint(f);
  x += 0x7fff + ((x >> 16) & 1);
  return (ushort)(x >> 16);
}
__device__ __forceinline__ bf16x8 mk8(ushort4 a0, ushort4 a1) {
  bf16x8 v;
  v[0] = (short)a0.x; v[1] = (short)a0.y; v[2] = (short)a0.z; v[3] = (short)a0.w;
  v[4] = (short)a1.x; v[5] = (short)a1.y; v[6] = (short)a1.z; v[7] = (short)a1.w;
  return v;
}

// ---------------- fused fp32 -> bf16 convert (x, w_attn, w_proj in one launch) ----------------
__global__ void cvt3(const float* __restrict__ x, const float* __restrict__ wa,
                     const float* __restrict__ wp, ushort* __restrict__ xb,
                     ushort* __restrict__ wab, ushort* __restrict__ wpb) {
  const int stride = gridDim.x * blockDim.x;
  for (int i = blockIdx.x * blockDim.x + threadIdx.x; i < 3145728; i += stride) {
    const float* src; ushort* dst; int off;
    if (i < 2097152) { src = x; dst = xb; off = i; }
    else if (i < 2883584) { src = wa; dst = wab; off = i - 2097152; }
    else { src = wp; dst = wpb; off = i - 2883584; }
    float4 v = ((const float4*)src)[off];
    ushort4 o;
    o.x = f2bf(v.x); o.y = f2bf(v.y); o.z = f2bf(v.z); o.w = f2bf(v.w);
    ((ushort4*)dst)[off] = o;
  }
}

// ---------------- bf16 GEMM (r2-proven reg-staged, pad-68):  C = A * Bw^T ----------------
template <bool OUT_BF16>
__global__ __launch_bounds__(256) void gemm_bt(const ushort* __restrict__ A,
                                               const ushort* __restrict__ Bw,
                                               void* __restrict__ Cout,
                                               int M, int N, int K) {
  __shared__ ushort As[128][68];
  __shared__ ushort Bs[128][68];
  const int m0 = blockIdx.y * 128;
  const int n0 = blockIdx.x * 128;
  const int tid = threadIdx.x;
  const int lane = tid & 63;
  const int wv = tid >> 6;
  const int wr = wv >> 1, wc = wv & 1;
  const int lo = lane & 15, hi = lane >> 4;

  f32x4 acc[4][4];
#pragma unroll
  for (int i = 0; i < 4; ++i)
#pragma unroll
    for (int j = 0; j < 4; ++j) acc[i][j] = (f32x4)0.0f;

  for (int k0 = 0; k0 < K; k0 += 64) {
    __syncthreads();
#pragma unroll
    for (int t = 0; t < 4; ++t) {
      int c = tid + 256 * t;
      int row = c >> 3, cc = c & 7;
      uint4 va = *(const uint4*)(A + (size_t)(m0 + row) * K + k0 + cc * 8);
      *(uint2*)&As[row][cc * 8]     = make_uint2(va.x, va.y);
      *(uint2*)&As[row][cc * 8 + 4] = make_uint2(va.z, va.w);
      uint4 vb = *(const uint4*)(Bw + (size_t)(n0 + row) * K + k0 + cc * 8);
      *(uint2*)&Bs[row][cc * 8]     = make_uint2(vb.x, vb.y);
      *(uint2*)&Bs[row][cc * 8 + 4] = make_uint2(vb.z, vb.w);
    }
    __syncthreads();
#pragma unroll
    for (int kk = 0; kk < 64; kk += 32) {
      bf16x8 af[4], bfr[4];
#pragma unroll
      for (int i = 0; i < 4; ++i) {
        int r = wr * 64 + i * 16 + lo;
        af[i] = mk8(*(const ushort4*)&As[r][kk + 4 * hi],
                    *(const ushort4*)&As[r][kk + 16 + 4 * hi]);
      }
#pragma unroll
      for (int j = 0; j < 4; ++j) {
        int r = wc * 64 + j * 16 + lo;
        bfr[j] = mk8(*(const ushort4*)&Bs[r][kk + 4 * hi],
                     *(const ushort4*)&Bs[r][kk + 16 + 4 * hi]);
      }
#pragma unroll
      for (int i = 0; i < 4; ++i)
#pragma unroll
        for (int j = 0; j < 4; ++j)
          acc[i][j] = __builtin_amdgcn_mfma_f32_16x16x32_bf16(af[i], bfr[j], acc[i][j], 0, 0, 0);
    }
  }
#pragma unroll
  for (int i = 0; i < 4; ++i) {
    int row = m0 + wr * 64 + i * 16 + 4 * hi;
#pragma unroll
    for (int j = 0; j < 4; ++j) {
      int col = n0 + wc * 64 + j * 16 + lo;
#pragma unroll
      for (int r = 0; r < 4; ++r) {
        float v = acc[i][j][r];
        if constexpr (OUT_BF16) {
          ((ushort*)Cout)[(size_t)(row + r) * N + col] = f2bf(v);
        } else {
          ((float*)Cout)[(size_t)(row + r) * N + col] = v;
        }
      }
    }
  }
}

// ---------------- fused RoPE + mean + causal attention per (b,h,g) ----------------
// Staging loop ropes q/k in registers (float4 fc/fs loads) and accumulates fp32
// mean partials; 3-shfl + tiny LDS reduce produces the mean token; then the
// swapped-operand MFMA attention runs unchanged.
__global__ __launch_bounds__(256) void attn1f(const ushort* __restrict__ qkv,
                                              const float* __restrict__ fc,
                                              const float* __restrict__ fs,
                                              ushort* __restrict__ xo, float* __restrict__ attm,
                                              float* __restrict__ yq, float* __restrict__ yk) {
  __shared__ ushort qs[144][68];
  __shared__ ushort ks[144][68];
  __shared__ ushort vt[64][148];   // V^T: vt[d][key]
  __shared__ ushort obuf[4][16][68];   // phase C; aliased as redL (3 KB) for the mean reduce
  float (*redL)[8][24] = reinterpret_cast<float(*)[8][24]>(&obuf[0][0][0]);
  const int blk = blockIdx.x;
  const int g = blk & 15, h = (blk >> 4) & 15, b = blk >> 8;
  const int tid = threadIdx.x;
  const int lane = tid & 63, wv = tid >> 6;
  const int lo = lane & 15, hi = lane >> 4;

  // zero V^T pad keys 128..147 (write-disjoint from staging: keys 0..127) — no barrier
  for (int idx = tid; idx < 320; idx += 256) {
    int d = idx / 5, ch = (idx % 5) * 4;
    *(ushort4*)&vt[d][128 + ch] = make_ushort4(0, 0, 0, 0);
  }

  // fused stage + rope + mean-partials (rows 0..127; each thread owns cols c8..c8+7)
  const size_t rowbase = (size_t)(b * TT + g * TG) * (3 * CC) + h * HS;
  const int srow = tid >> 3;          // 0..31
  const int c8 = (tid & 7) * 8;
  float msq[8], msk[8], msv[8];
#pragma unroll
  for (int j = 0; j < 8; ++j) { msq[j] = 0.f; msk[j] = 0.f; msv[j] = 0.f; }
#pragma unroll
  for (int it = 0; it < 12; ++it) {
    const int part = it >> 2;          // 0:q 1:k 2:v (compile-time after unroll)
    const int s = srow + 32 * (it & 3);
    uint4 w = *(const uint4*)(qkv + rowbase + (size_t)s * (3 * CC) + part * CC + c8);
    ushort e[8];
    *(uint4*)e = w;
    if (part == 2) {
#pragma unroll
      for (int j = 0; j < 8; ++j) { msv[j] += bf2f(e[j]); vt[c8 + j][s] = e[j]; }
    } else {
      const int ts = g * TG + s;
      float4 cv = *(const float4*)&fc[ts * 32 + (c8 >> 1)];
      float4 sv = *(const float4*)&fs[ts * 32 + (c8 >> 1)];
      float a0 = bf2f(e[0]), a1 = bf2f(e[1]), a2 = bf2f(e[2]), a3 = bf2f(e[3]);
      float a4 = bf2f(e[4]), a5 = bf2f(e[5]), a6 = bf2f(e[6]), a7 = bf2f(e[7]);
      float r0 = a0 * cv.x - a1 * sv.x, r1 = a0 * sv.x + a1 * cv.x;
      float r2 = a2 * cv.y - a3 * sv.y, r3 = a2 * sv.y + a3 * cv.y;
      float r4 = a4 * cv.z - a5 * sv.z, r5 = a4 * sv.z + a5 * cv.z;
      float r6 = a6 * cv.w - a7 * sv.w, r7 = a6 * sv.w + a7 * cv.w;
      uint4 o;
      o.x = (unsigned)f2bf(r0) | ((unsigned)f2bf(r1) << 16);
      o.y = (unsigned)f2bf(r2) | ((unsigned)f2bf(r3) << 16);
      o.z = (unsigned)f2bf(r4) | ((unsigned)f2bf(r5) << 16);
      o.w = (unsigned)f2bf(r6) | ((unsigned)f2bf(r7) << 16);
      if (part == 0) {
        *(uint4*)&qs[s][c8] = o;
        msq[0] += r0; msq[1] += r1; msq[2] += r2; msq[3] += r3;
        msq[4] += r4; msq[5] += r5; msq[6] += r6; msq[7] += r7;
      } else {
        *(uint4*)&ks[s][c8] = o;
        msk[0] += r0; msk[1] += r1; msk[2] += r2; msk[3] += r3;
        msk[4] += r4; msk[5] += r5; msk[6] += r6; msk[7] += r7;
      }
    }
  }
  // reduce over s within wave (lanes ⊕8,16,32 share c8), then cross-wave via redL
#pragma unroll
  for (int j = 0; j < 8; ++j) {
    msq[j] += __shfl_xor(msq[j], 8); msq[j] += __shfl_xor(msq[j], 16); msq[j] += __shfl_xor(msq[j], 32);
    msk[j] += __shfl_xor(msk[j], 8); msk[j] += __shfl_xor(msk[j], 16); msk[j] += __shfl_xor(msk[j], 32);
    msv[j] += __shfl_xor(msv[j], 8); msv[j] += __shfl_xor(msv[j], 16); msv[j] += __shfl_xor(msv[j], 32);
  }
  if (lane < 8) {
#pragma unroll
    for (int j = 0; j < 8; ++j) {
      redL[wv][lane][j] = msq[j];
      redL[wv][lane][8 + j] = msk[j];
      redL[wv][lane][16 + j] = msv[j];
    }
  }
  __syncthreads();
  if (tid < 64) {
    const int cg = tid >> 3, j = tid & 7;
    float mq = (redL[0][cg][j] + redL[1][cg][j] + redL[2][cg][j] + redL[3][cg][j]) * (1.0f / 128.0f);
    float mk2 = (redL[0][cg][8 + j] + redL[1][cg][8 + j] + redL[2][cg][8 + j] + redL[3][cg][8 + j]) * (1.0f / 128.0f);
    float mv = (redL[0][cg][16 + j] + redL[1][cg][16 + j] + redL[2][cg][16 + j] + redL[3][cg][16 + j]) * (1.0f / 128.0f);
    qs[128][tid] = f2bf(mq);
    ks[128][tid] = f2bf(mk2);
    vt[tid][128] = f2bf(mv);
    if (g < 15) {
      size_t yo = ((size_t)(b * 16 + h) * 15 + g) * 64 + tid;
      yq[yo] = mq; yk[yo] = mk2;
    }
  }
  __syncthreads();

  // attention (stale qs/ks rows 129..143 contained by masking / discarded cols)
#pragma unroll
  for (int ti = 0; ti < 3; ++ti) {
    const int t = (ti == 0) ? (8 - wv)
                : (ti == 1) ? ((wv == 3) ? 4 : (wv + 1))
                            : ((wv == 3) ? 0 : -1);
    if (t < 0) continue;
    const int q0 = t * 16;

    bf16x8 bq[2];
#pragma unroll
    for (int k2 = 0; k2 < 2; ++k2)
      bq[k2] = mk8(*(const ushort4*)&qs[q0 + lo][k2 * 32 + 4 * hi],
                   *(const ushort4*)&qs[q0 + lo][k2 * 32 + 16 + 4 * hi]);

    f32x4 sc[9];
#pragma unroll
    for (int n = 0; n < 9; ++n) sc[n] = (f32x4)0.0f;
#pragma unroll
    for (int n = 0; n < 9; ++n) {
      if (n > t) continue;
#pragma unroll
      for (int k2 = 0; k2 < 2; ++k2) {
        bf16x8 ak = mk8(*(const ushort4*)&ks[n * 16 + lo][k2 * 32 + 4 * hi],
                        *(const ushort4*)&ks[n * 16 + lo][k2 * 32 + 16 + 4 * hi]);
        sc[n] = __builtin_amdgcn_mfma_f32_16x16x32_bf16(ak, bq[k2], sc[n], 0, 0, 0);
      }
    }

    const int qi = q0 + lo;
    float mx = -INFINITY;
#pragma unroll
    for (int n = 0; n < 9; ++n) {
      if (n > t) continue;
#pragma unroll
      for (int r = 0; r < 4; ++r) {
        int kj = n * 16 + 4 * hi + r;
        float v = (kj <= qi) ? sc[n][r] * 0.125f : -INFINITY;
        sc[n][r] = v;
        mx = fmaxf(mx, v);
      }
    }
    mx = fmaxf(mx, __shfl_xor(mx, 16));
    mx = fmaxf(mx, __shfl_xor(mx, 32));
    float sum = 0.f;
#pragma unroll
    for (int n = 0; n < 9; ++n) {
      if (n > t) continue;
#pragma unroll
      for (int r = 0; r < 4; ++r) {
        float e = __expf(sc[n][r] - mx);
        sc[n][r] = e;
        sum += e;
      }
    }
    sum += __shfl_xor(sum, 16);
    sum += __shfl_xor(sum, 32);
    const float inv = 1.0f / sum;

    f32x4 oac[4];
#pragma unroll
    for (int m = 0; m < 4; ++m) oac[m] = (f32x4)0.0f;
#pragma unroll
    for (int s2 = 0; s2 < 5; ++s2) {
      if (s2 > (t >> 1)) continue;
      const int kt1ok = (2 * s2 + 1 <= t);
      bf16x8 pb;
#pragma unroll
      for (int e = 0; e < 4; ++e) pb[e] = (short)f2bf(sc[2 * s2][e] * inv);
      if (kt1ok) {
#pragma unroll
        for (int e = 0; e < 4; ++e) pb[e + 4] = (short)f2bf(sc[2 * s2 + 1][e] * inv);
      } else {
#pragma unroll
        for (int e = 0; e < 4; ++e) pb[e + 4] = 0;
      }
#pragma unroll
      for (int m = 0; m < 4; ++m) {
        ushort4 a0 = *(const ushort4*)&vt[m * 16 + lo][32 * s2 + 4 * hi];
        ushort4 a1 = kt1ok ? *(const ushort4*)&vt[m * 16 + lo][32 * s2 + 16 + 4 * hi]
                           : make_ushort4(0, 0, 0, 0);
        oac[m] = __builtin_amdgcn_mfma_f32_16x16x32_bf16(mk8(a0, a1), pb, oac[m], 0, 0, 0);
      }
    }

    if (t < 8) {
#pragma unroll
      for (int m = 0; m < 4; ++m)
#pragma unroll
        for (int r = 0; r < 4; ++r)
          obuf[wv][lo][m * 16 + 4 * hi + r] = f2bf(oac[m][r]);
#pragma unroll
      for (int it = 0; it < 4; ++it) {
        int idx = lane + 64 * it;
        int r = idx >> 4;
        int c4 = (idx & 15) * 4;
        uint2 val = *(const uint2*)&obuf[wv][r][c4];
        int tok = g * TG + t * 16 + r;
        *(uint2*)(xo + ((size_t)(b * TT + tok)) * CC + h * HS + c4) = val;
      }
    } else {
      if (lo == 0) {
#pragma unroll
        for (int m = 0; m < 4; ++m)
#pragma unroll
          for (int r = 0; r < 4; ++r)
            attm[(size_t)blk * 64 + m * 16 + 4 * hi + r] = oac[m][r];
      }
    }
  }
}

// ---------------- second (tiny) causal attention over 15 group-mean tokens ----------------
__global__ __launch_bounds__(64) void attn2(const float* __restrict__ yq,
                                            const float* __restrict__ yk,
                                            const float* __restrict__ attm,
                                            float* __restrict__ yv) {
  __shared__ float qs2[15][64], ks2[15][64], avs[15][64], srow[16];
  int bh = blockIdx.x, lane = threadIdx.x;
  for (int j = 0; j < 15; ++j) {
    qs2[j][lane] = yq[((size_t)bh * 15 + j) * 64 + lane];
    ks2[j][lane] = yk[((size_t)bh * 15 + j) * 64 + lane];
    avs[j][lane] = attm[((size_t)bh * 16 + j) * 64 + lane];
  }
  __syncthreads();
  for (int i = 0; i < 15; ++i) {
    float qv = qs2[i][lane];
    for (int j = 0; j <= i; ++j) {
      float t = qv * ks2[j][lane];
#pragma unroll
      for (int off = 32; off > 0; off >>= 1) t += __shfl_xor(t, off);
      if (lane == 0) srow[j] = t * 0.125f;
    }
    __syncthreads();
    float mx = -INFINITY;
    for (int j = 0; j <= i; ++j) mx = fmaxf(mx, srow[j]);
    float den = 0;
    for (int j = 0; j <= i; ++j) den += __expf(srow[j] - mx);
    float inv = 1.0f / den;
    float o = 0;
    for (int j = 0; j <= i; ++j) o += __expf(srow[j] - mx) * inv * avs[j][lane];
    yv[((size_t)bh * 15 + i) * 64 + lane] = o;
    __syncthreads();
  }
}

extern "C" void kernel_launch(void* const* d_in, const int* in_sizes, int n_in,
                              void* d_out, int out_size, void* d_ws, size_t ws_size,
                              hipStream_t stream) {
  const float* x      = (const float*)d_in[0];
  const float* w_attn = (const float*)d_in[1];
  const float* w_proj = (const float*)d_in[2];
  const float* fc     = (const float*)d_in[3];
  const float* fs     = (const float*)d_in[4];
  float* out = (float*)d_out;

  char* ws = (char*)d_ws;
  ushort* xb   = (ushort*)(ws);               // x bf16; dead after qkv gemm
  ushort* xo   = (ushort*)(ws);               // reuse xb region (attn1f output)
  ushort* wab  = (ushort*)(ws + 16777216);    // dead after qkv gemm
  float*  attm = (float*) (ws + 16777216);    // reuse wab region
  ushort* wpb  = (ushort*)(ws + 23068672);
  ushort* qkv  = (ushort*)(ws + 25165824);    // (B*T) x 3C bf16 -> end 75,497,472

  float* yq = out + 8388608;
  float* yk = out + 8450048;
  float* yv = out + 8511488;

  cvt3<<<2048, 256, 0, stream>>>(x, w_attn, w_proj, xb, wab, wpb);
  gemm_bt<true><<<dim3(24, 64), 256, 0, stream>>>(xb, wab, qkv, 8192, 3072, 1024);
  attn1f<<<1024, 256, 0, stream>>>(qkv, fc, fs, xo, attm, yq, yk);
  attn2<<<64, 64, 0, stream>>>(yq, yk, attm, yv);
  gemm_bt<false><<<dim3(8, 64), 256, 0, stream>>>(xo, wpb, out, 8192, 1024, 1024);
}

// Round 16
// 177.072 us; speedup vs baseline: 1.2499x; 1.0266x over previous
//
#include <hip/hip_runtime.h>
#include <hip/hip_bf16.h>

#define HS 64
#define NH 16
#define NG 16
#define TT 2048
#define CC 1024
#define BBATCH 4
#define TG 128
#define SS 129   // TG+1

typedef __attribute__((ext_vector_type(8))) short bf16x8;
typedef __attribute__((ext_vector_type(4))) float f32x4;

__device__ __forceinline__ float bf2f(ushort u) {
  return __uint_as_float(((unsigned)u) << 16);
}
__device__ __forceinline__ ushort f2bf(float f) {
  unsigned x = __float_as_uint(f);
  x += 0x7fff + ((x >> 16) & 1);
  return (ushort)(x >> 16);
}
__device__ __forceinline__ bf16x8 mk8(ushort4 a0, ushort4 a1) {
  bf16x8 v;
  v[0] = (short)a0.x; v[1] = (short)a0.y; v[2] = (short)a0.z; v[3] = (short)a0.w;
  v[4] = (short)a1.x; v[5] = (short)a1.y; v[6] = (short)a1.z; v[7] = (short)a1.w;
  return v;
}

// ---------------- fused fp32 -> bf16 convert (x, w_attn, w_proj in one launch) ----------------
__global__ void cvt3(const float* __restrict__ x, const float* __restrict__ wa,
                     const float* __restrict__ wp, ushort* __restrict__ xb,
                     ushort* __restrict__ wab, ushort* __restrict__ wpb) {
  const int stride = gridDim.x * blockDim.x;
  for (int i = blockIdx.x * blockDim.x + threadIdx.x; i < 3145728; i += stride) {
    const float* src; ushort* dst; int off;
    if (i < 2097152) { src = x; dst = xb; off = i; }
    else if (i < 2883584) { src = wa; dst = wab; off = i - 2097152; }
    else { src = wp; dst = wpb; off = i - 2883584; }
    float4 v = ((const float4*)src)[off];
    ushort4 o;
    o.x = f2bf(v.x); o.y = f2bf(v.y); o.z = f2bf(v.z); o.w = f2bf(v.w);
    ((ushort4*)dst)[off] = o;
  }
}

// ---------------- bf16 GEMM (r2-proven reg-staged, pad-68):  C = A * Bw^T ----------------
template <bool OUT_BF16>
__global__ __launch_bounds__(256) void gemm_bt(const ushort* __restrict__ A,
                                               const ushort* __restrict__ Bw,
                                               void* __restrict__ Cout,
                                               int M, int N, int K) {
  __shared__ ushort As[128][68];
  __shared__ ushort Bs[128][68];
  const int m0 = blockIdx.y * 128;
  const int n0 = blockIdx.x * 128;
  const int tid = threadIdx.x;
  const int lane = tid & 63;
  const int wv = tid >> 6;
  const int wr = wv >> 1, wc = wv & 1;
  const int lo = lane & 15, hi = lane >> 4;

  f32x4 acc[4][4];
#pragma unroll
  for (int i = 0; i < 4; ++i)
#pragma unroll
    for (int j = 0; j < 4; ++j) acc[i][j] = (f32x4)0.0f;

  for (int k0 = 0; k0 < K; k0 += 64) {
    __syncthreads();
#pragma unroll
    for (int t = 0; t < 4; ++t) {
      int c = tid + 256 * t;
      int row = c >> 3, cc = c & 7;
      uint4 va = *(const uint4*)(A + (size_t)(m0 + row) * K + k0 + cc * 8);
      *(uint2*)&As[row][cc * 8]     = make_uint2(va.x, va.y);
      *(uint2*)&As[row][cc * 8 + 4] = make_uint2(va.z, va.w);
      uint4 vb = *(const uint4*)(Bw + (size_t)(n0 + row) * K + k0 + cc * 8);
      *(uint2*)&Bs[row][cc * 8]     = make_uint2(vb.x, vb.y);
      *(uint2*)&Bs[row][cc * 8 + 4] = make_uint2(vb.z, vb.w);
    }
    __syncthreads();
#pragma unroll
    for (int kk = 0; kk < 64; kk += 32) {
      bf16x8 af[4], bfr[4];
#pragma unroll
      for (int i = 0; i < 4; ++i) {
        int r = wr * 64 + i * 16 + lo;
        af[i] = mk8(*(const ushort4*)&As[r][kk + 4 * hi],
                    *(const ushort4*)&As[r][kk + 16 + 4 * hi]);
      }
#pragma unroll
      for (int j = 0; j < 4; ++j) {
        int r = wc * 64 + j * 16 + lo;
        bfr[j] = mk8(*(const ushort4*)&Bs[r][kk + 4 * hi],
                     *(const ushort4*)&Bs[r][kk + 16 + 4 * hi]);
      }
#pragma unroll
      for (int i = 0; i < 4; ++i)
#pragma unroll
        for (int j = 0; j < 4; ++j)
          acc[i][j] = __builtin_amdgcn_mfma_f32_16x16x32_bf16(af[i], bfr[j], acc[i][j], 0, 0, 0);
    }
  }
#pragma unroll
  for (int i = 0; i < 4; ++i) {
    int row = m0 + wr * 64 + i * 16 + 4 * hi;
#pragma unroll
    for (int j = 0; j < 4; ++j) {
      int col = n0 + wc * 64 + j * 16 + lo;
#pragma unroll
      for (int r = 0; r < 4; ++r) {
        float v = acc[i][j][r];
        if constexpr (OUT_BF16) {
          ((ushort*)Cout)[(size_t)(row + r) * N + col] = f2bf(v);
        } else {
          ((float*)Cout)[(size_t)(row + r) * N + col] = v;
        }
      }
    }
  }
}

// ---------------- fused RoPE + mean + causal attention per (b,h,g) — 8 waves ----------------
// 512 threads: staging/rope/mean split over 8 waves; attention 1 q-tile per wave
// (wave w -> t=8-w; wave 7 also t=0). 73.8 KB LDS -> 2 blocks/CU = 16 waves/CU.
__global__ __launch_bounds__(512, 4) void attn1f(const ushort* __restrict__ qkv,
                                                 const float* __restrict__ fc,
                                                 const float* __restrict__ fs,
                                                 ushort* __restrict__ xo, float* __restrict__ attm,
                                                 float* __restrict__ yq, float* __restrict__ yk) {
  __shared__ ushort qs[144][68];
  __shared__ ushort ks[144][68];
  __shared__ ushort vt[64][148];     // V^T: vt[d][key]
  __shared__ ushort obuf[8][16][68]; // phase C; aliased as redL (6 KB) for the mean reduce
  float (*redL)[8][24] = reinterpret_cast<float(*)[8][24]>(&obuf[0][0][0]);
  const int blk = blockIdx.x;
  const int g = blk & 15, h = (blk >> 4) & 15, b = blk >> 8;
  const int tid = threadIdx.x;
  const int lane = tid & 63, wv = tid >> 6;
  const int lo = lane & 15, hi = lane >> 4;

  // zero V^T pad keys 128..147 (write-disjoint from staging) — no barrier needed
  if (tid < 320) {
    int d = tid / 5, ch = (tid % 5) * 4;
    *(ushort4*)&vt[d][128 + ch] = make_ushort4(0, 0, 0, 0);
  }

  // fused stage + rope + mean-partials (rows 0..127; thread owns cols c8..c8+7)
  const size_t rowbase = (size_t)(b * TT + g * TG) * (3 * CC) + h * HS;
  const int srow = tid >> 3;          // 0..63
  const int c8 = (tid & 7) * 8;
  float msq[8], msk[8], msv[8];
#pragma unroll
  for (int j = 0; j < 8; ++j) { msq[j] = 0.f; msk[j] = 0.f; msv[j] = 0.f; }
#pragma unroll
  for (int it = 0; it < 6; ++it) {
    const int part = it >> 1;          // 0:q 1:k 2:v (compile-time after unroll)
    const int s = srow + 64 * (it & 1);
    uint4 w = *(const uint4*)(qkv + rowbase + (size_t)s * (3 * CC) + part * CC + c8);
    ushort e[8];
    *(uint4*)e = w;
    if (part == 2) {
#pragma unroll
      for (int j = 0; j < 8; ++j) { msv[j] += bf2f(e[j]); vt[c8 + j][s] = e[j]; }
    } else {
      const int ts = g * TG + s;
      float4 cv = *(const float4*)&fc[ts * 32 + (c8 >> 1)];
      float4 sv = *(const float4*)&fs[ts * 32 + (c8 >> 1)];
      float a0 = bf2f(e[0]), a1 = bf2f(e[1]), a2 = bf2f(e[2]), a3 = bf2f(e[3]);
      float a4 = bf2f(e[4]), a5 = bf2f(e[5]), a6 = bf2f(e[6]), a7 = bf2f(e[7]);
      float r0 = a0 * cv.x - a1 * sv.x, r1 = a0 * sv.x + a1 * cv.x;
      float r2 = a2 * cv.y - a3 * sv.y, r3 = a2 * sv.y + a3 * cv.y;
      float r4 = a4 * cv.z - a5 * sv.z, r5 = a4 * sv.z + a5 * cv.z;
      float r6 = a6 * cv.w - a7 * sv.w, r7 = a6 * sv.w + a7 * cv.w;
      uint4 o;
      o.x = (unsigned)f2bf(r0) | ((unsigned)f2bf(r1) << 16);
      o.y = (unsigned)f2bf(r2) | ((unsigned)f2bf(r3) << 16);
      o.z = (unsigned)f2bf(r4) | ((unsigned)f2bf(r5) << 16);
      o.w = (unsigned)f2bf(r6) | ((unsigned)f2bf(r7) << 16);
      if (part == 0) {
        *(uint4*)&qs[s][c8] = o;
        msq[0] += r0; msq[1] += r1; msq[2] += r2; msq[3] += r3;
        msq[4] += r4; msq[5] += r5; msq[6] += r6; msq[7] += r7;
      } else {
        *(uint4*)&ks[s][c8] = o;
        msk[0] += r0; msk[1] += r1; msk[2] += r2; msk[3] += r3;
        msk[4] += r4; msk[5] += r5; msk[6] += r6; msk[7] += r7;
      }
    }
  }
  // reduce over s within wave (lanes ⊕8,16,32 share c8), then cross-wave via redL
#pragma unroll
  for (int j = 0; j < 8; ++j) {
    msq[j] += __shfl_xor(msq[j], 8); msq[j] += __shfl_xor(msq[j], 16); msq[j] += __shfl_xor(msq[j], 32);
    msk[j] += __shfl_xor(msk[j], 8); msk[j] += __shfl_xor(msk[j], 16); msk[j] += __shfl_xor(msk[j], 32);
    msv[j] += __shfl_xor(msv[j], 8); msv[j] += __shfl_xor(msv[j], 16); msv[j] += __shfl_xor(msv[j], 32);
  }
  if (lane < 8) {
#pragma unroll
    for (int j = 0; j < 8; ++j) {
      redL[wv][lane][j] = msq[j];
      redL[wv][lane][8 + j] = msk[j];
      redL[wv][lane][16 + j] = msv[j];
    }
  }
  __syncthreads();
  if (tid < 64) {
    const int cg = tid >> 3, j = tid & 7;
    float mq = 0.f, mk2 = 0.f, mv = 0.f;
#pragma unroll
    for (int w = 0; w < 8; ++w) {
      mq += redL[w][cg][j];
      mk2 += redL[w][cg][8 + j];
      mv += redL[w][cg][16 + j];
    }
    mq *= (1.0f / 128.0f); mk2 *= (1.0f / 128.0f); mv *= (1.0f / 128.0f);
    qs[128][tid] = f2bf(mq);
    ks[128][tid] = f2bf(mk2);
    vt[tid][128] = f2bf(mv);
    if (g < 15) {
      size_t yo = ((size_t)(b * 16 + h) * 15 + g) * 64 + tid;
      yq[yo] = mq; yk[yo] = mk2;
    }
  }
  __syncthreads();

  // attention: wave wv -> tile t=8-wv; wave 7 also t=0.
  // (stale qs/ks rows 129..143 contained by masking / discarded garbage-query cols)
#pragma unroll
  for (int ti = 0; ti < 2; ++ti) {
    const int t = (ti == 0) ? (8 - wv) : ((wv == 7) ? 0 : -1);
    if (t < 0) continue;
    const int q0 = t * 16;

    bf16x8 bq[2];
#pragma unroll
    for (int k2 = 0; k2 < 2; ++k2)
      bq[k2] = mk8(*(const ushort4*)&qs[q0 + lo][k2 * 32 + 4 * hi],
                   *(const ushort4*)&qs[q0 + lo][k2 * 32 + 16 + 4 * hi]);

    f32x4 sc[9];
#pragma unroll
    for (int n = 0; n < 9; ++n) sc[n] = (f32x4)0.0f;
#pragma unroll
    for (int n = 0; n < 9; ++n) {
      if (n > t) continue;
#pragma unroll
      for (int k2 = 0; k2 < 2; ++k2) {
        bf16x8 ak = mk8(*(const ushort4*)&ks[n * 16 + lo][k2 * 32 + 4 * hi],
                        *(const ushort4*)&ks[n * 16 + lo][k2 * 32 + 16 + 4 * hi]);
        sc[n] = __builtin_amdgcn_mfma_f32_16x16x32_bf16(ak, bq[k2], sc[n], 0, 0, 0);
      }
    }

    const int qi = q0 + lo;
    float mx = -INFINITY;
#pragma unroll
    for (int n = 0; n < 9; ++n) {
      if (n > t) continue;
#pragma unroll
      for (int r = 0; r < 4; ++r) {
        int kj = n * 16 + 4 * hi + r;
        float v = (kj <= qi) ? sc[n][r] * 0.125f : -INFINITY;
        sc[n][r] = v;
        mx = fmaxf(mx, v);
      }
    }
    mx = fmaxf(mx, __shfl_xor(mx, 16));
    mx = fmaxf(mx, __shfl_xor(mx, 32));
    float sum = 0.f;
#pragma unroll
    for (int n = 0; n < 9; ++n) {
      if (n > t) continue;
#pragma unroll
      for (int r = 0; r < 4; ++r) {
        float e = __expf(sc[n][r] - mx);
        sc[n][r] = e;
        sum += e;
      }
    }
    sum += __shfl_xor(sum, 16);
    sum += __shfl_xor(sum, 32);
    const float inv = 1.0f / sum;

    f32x4 oac[4];
#pragma unroll
    for (int m = 0; m < 4; ++m) oac[m] = (f32x4)0.0f;
#pragma unroll
    for (int s2 = 0; s2 < 5; ++s2) {
      if (s2 > (t >> 1)) continue;
      const int kt1ok = (2 * s2 + 1 <= t);
      bf16x8 pb;
#pragma unroll
      for (int e = 0; e < 4; ++e) pb[e] = (short)f2bf(sc[2 * s2][e] * inv);
      if (kt1ok) {
#pragma unroll
        for (int e = 0; e < 4; ++e) pb[e + 4] = (short)f2bf(sc[2 * s2 + 1][e] * inv);
      } else {
#pragma unroll
        for (int e = 0; e < 4; ++e) pb[e + 4] = 0;
      }
#pragma unroll
      for (int m = 0; m < 4; ++m) {
        ushort4 a0 = *(const ushort4*)&vt[m * 16 + lo][32 * s2 + 4 * hi];
        ushort4 a1 = kt1ok ? *(const ushort4*)&vt[m * 16 + lo][32 * s2 + 16 + 4 * hi]
                           : make_ushort4(0, 0, 0, 0);
        oac[m] = __builtin_amdgcn_mfma_f32_16x16x32_bf16(mk8(a0, a1), pb, oac[m], 0, 0, 0);
      }
    }

    if (t < 8) {
#pragma unroll
      for (int m = 0; m < 4; ++m)
#pragma unroll
        for (int r = 0; r < 4; ++r)
          obuf[wv][lo][m * 16 + 4 * hi + r] = f2bf(oac[m][r]);
#pragma unroll
      for (int it = 0; it < 4; ++it) {
        int idx = lane + 64 * it;
        int r = idx >> 4;
        int c4 = (idx & 15) * 4;
        uint2 val = *(const uint2*)&obuf[wv][r][c4];
        int tok = g * TG + t * 16 + r;
        *(uint2*)(xo + ((size_t)(b * TT + tok)) * CC + h * HS + c4) = val;
      }
    } else {
      if (lo == 0) {
#pragma unroll
        for (int m = 0; m < 4; ++m)
#pragma unroll
          for (int r = 0; r < 4; ++r)
            attm[(size_t)blk * 64 + m * 16 + 4 * hi + r] = oac[m][r];
      }
    }
  }
}

// ---------------- second (tiny) causal attention over 15 group-mean tokens ----------------
__global__ __launch_bounds__(64) void attn2(const float* __restrict__ yq,
                                            const float* __restrict__ yk,
                                            const float* __restrict__ attm,
                                            float* __restrict__ yv) {
  __shared__ float qs2[15][64], ks2[15][64], avs[15][64], srow[16];
  int bh = blockIdx.x, lane = threadIdx.x;
  for (int j = 0; j < 15; ++j) {
    qs2[j][lane] = yq[((size_t)bh * 15 + j) * 64 + lane];
    ks2[j][lane] = yk[((size_t)bh * 15 + j) * 64 + lane];
    avs[j][lane] = attm[((size_t)bh * 16 + j) * 64 + lane];
  }
  __syncthreads();
  for (int i = 0; i < 15; ++i) {
    float qv = qs2[i][lane];
    for (int j = 0; j <= i; ++j) {
      float t = qv * ks2[j][lane];
#pragma unroll
      for (int off = 32; off > 0; off >>= 1) t += __shfl_xor(t, off);
      if (lane == 0) srow[j] = t * 0.125f;
    }
    __syncthreads();
    float mx = -INFINITY;
    for (int j = 0; j <= i; ++j) mx = fmaxf(mx, srow[j]);
    float den = 0;
    for (int j = 0; j <= i; ++j) den += __expf(srow[j] - mx);
    float inv = 1.0f / den;
    float o = 0;
    for (int j = 0; j <= i; ++j) o += __expf(srow[j] - mx) * inv * avs[j][lane];
    yv[((size_t)bh * 15 + i) * 64 + lane] = o;
    __syncthreads();
  }
}

extern "C" void kernel_launch(void* const* d_in, const int* in_sizes, int n_in,
                              void* d_out, int out_size, void* d_ws, size_t ws_size,
                              hipStream_t stream) {
  const float* x      = (const float*)d_in[0];
  const float* w_attn = (const float*)d_in[1];
  const float* w_proj = (const float*)d_in[2];
  const float* fc     = (const float*)d_in[3];
  const float* fs     = (const float*)d_in[4];
  float* out = (float*)d_out;

  char* ws = (char*)d_ws;
  ushort* xb   = (ushort*)(ws);               // x bf16; dead after qkv gemm
  ushort* xo   = (ushort*)(ws);               // reuse xb region (attn1f output)
  ushort* wab  = (ushort*)(ws + 16777216);    // dead after qkv gemm
  float*  attm = (float*) (ws + 16777216);    // reuse wab region
  ushort* wpb  = (ushort*)(ws + 23068672);
  ushort* qkv  = (ushort*)(ws + 25165824);    // (B*T) x 3C bf16 -> end 75,497,472

  float* yq = out + 8388608;
  float* yk = out + 8450048;
  float* yv = out + 8511488;

  cvt3<<<2048, 256, 0, stream>>>(x, w_attn, w_proj, xb, wab, wpb);
  gemm_bt<true><<<dim3(24, 64), 256, 0, stream>>>(xb, wab, qkv, 8192, 3072, 1024);
  attn1f<<<1024, 512, 0, stream>>>(qkv, fc, fs, xo, attm, yq, yk);
  attn2<<<64, 64, 0, stream>>>(yq, yk, attm, yv);
  gemm_bt<false><<<dim3(8, 64), 256, 0, stream>>>(xo, wpb, out, 8192, 1024, 1024);
}